// Round 5
// baseline (285.518 us; speedup 1.0000x reference)
//
#include <hip/hip_runtime.h>
#include <stdint.h>

// Stage1Assigner (RPN matcher + subsample + top-k per GT) for MI355X.
// B=8 images, A=200000 anchors, G=64 GTs, K=4, thresholds 0.3/0.7, 128 max pos.
//
// PRNG: JAX threefry, jax_threefry_partitionable=True:
//   keys[b] = threefry2x32((0,42),(0,b));  bits[a] = y0^y1 of threefry2x32(key_b,(0,a))
// Selection of 128 positives = 128 lexicographically smallest (bits>>9, a).
//
// R12 vs R11 (counter-driven): R11 k_main=121us but total=271us -> ~142us in
// SIX tail dispatches whose real compute is ~25us (gaps ~15us each on a strict
// dependency chain + 784-block redundant hist reads / Tstar searches). R12
// fuses the per-image scalar tail (zero+hist+binsel+collect+Tstar+count+out)
// into ONE kernel k_final, grid (B)=8 x 1024 threads. Unlike R10's failed
// fusion this EXCLUDES the large-grid phases (k_main, k_top4_merge stay
// parallel dispatches) and k_final holds no big per-lane arrays -> no spill
// (launch_bounds(1024,4): VGPR cap 128). Selected set after Tstar is provably
// <=128 anchors (binary search count is exact; keys unique), so the count
// phase is <=128x64 IoUs per image. 8 dispatches -> 4.
//
// Screen (R11, proven): thrG[gt] = max over 8 sampled slices of the
// 4th-of-lane-maxima of approx q = inter*rcp(uni); sample-4th <= global-4th.
//   t~ = bits(min(thrG - 16ulp, 0.7f - 8ulp)) - 8ulp  (rcp err <= ~2.5 ulp
//   << 16-ulp slack; 8-ulp product margin covers binade edges; denormal
//   flush -> never-skip; thrG=0 -> screen passes everything -> safe).
// k_main runs ONE screened exact pass over all pairs; survivors get exact f32
// div, exact >=0.7 bit, ballot-guarded u64 top-4 insert. All exact
// comparisons identical to R5..R11 -> bit-identical output.
// Value-0 fake entries (masked lanes insert vb=0 early) are displaced whenever
// a gt has >=4 anchors with iou>0 globally (guaranteed for uniform boxes).
//
// IoU is fp-contract(off) IEEE per-op: identical bits across all passes and
// matches XLA per-HLO rounding.

#pragma clang fp contract(off)

#define B_IMG 8
#define A_N 200000
#define G_N 64
#define K_TOP 4
#define MAX_POS 128
#define FINE_CAP 4096
#define AS 2048
#define NS 98            // ceil(200000/2048)
#define SUB_NS 8         // sampled slices for the threshold pass
#define WPS 32           // u64 ballot words per slice
#define NWORD 3136       // NS*WPS words of pos bits per image

typedef unsigned long long u64;
typedef unsigned int u32;

__device__ __forceinline__ u32 rotl32(u32 v, int n) { return (v << n) | (v >> (32 - n)); }

__device__ __forceinline__ void tf_round(u32& x0, u32& x1, int r) {
  x0 += x1; x1 = rotl32(x1, r); x1 ^= x0;
}

__device__ __forceinline__ void threefry2x32(u32 k0, u32 k1, u32& x0, u32& x1) {
  u32 ks2 = 0x1BD11BDAu ^ k0 ^ k1;
  x0 += k0; x1 += k1;
  tf_round(x0,x1,13); tf_round(x0,x1,15); tf_round(x0,x1,26); tf_round(x0,x1,6);
  x0 += k1; x1 += ks2 + 1u;
  tf_round(x0,x1,17); tf_round(x0,x1,29); tf_round(x0,x1,16); tf_round(x0,x1,24);
  x0 += ks2; x1 += k0 + 2u;
  tf_round(x0,x1,13); tf_round(x0,x1,15); tf_round(x0,x1,26); tf_round(x0,x1,6);
  x0 += k0; x1 += k1 + 3u;
  tf_round(x0,x1,17); tf_round(x0,x1,29); tf_round(x0,x1,16); tf_round(x0,x1,24);
  x0 += k1; x1 += ks2 + 4u;
  tf_round(x0,x1,13); tf_round(x0,x1,15); tf_round(x0,x1,26); tf_round(x0,x1,6);
  x0 += ks2; x1 += k0 + 5u;
}

__device__ __forceinline__ void image_key(int b, u32& kb0, u32& kb1) {
  u32 x0 = 0u, x1 = (u32)b;
  threefry2x32(0u, 42u, x0, x1);
  kb0 = x0; kb1 = x1;
}

__device__ __forceinline__ u32 rbits_for(u32 k0, u32 k1, u32 a) {
  u32 x0 = 0u, x1 = a;
  threefry2x32(k0, k1, x0, x1);
  return x0 ^ x1;
}

__device__ __forceinline__ void conv_box(float4 bx, float& x0, float& y0,
                                         float& x1, float& y1, float& area) {
  #pragma clang fp contract(off)
  x0 = bx.x - 0.5f * bx.z;
  y0 = bx.y - 0.5f * bx.w;
  x1 = bx.x + 0.5f * bx.z;
  y1 = bx.y + 0.5f * bx.w;
  area = (x1 - x0) * (y1 - y0);
}

__device__ __forceinline__ float iou_pair(float ax0, float ay0, float ax1, float ay1, float aarea,
                                          float gx0, float gy0, float gx1, float gy1, float garea) {
  #pragma clang fp contract(off)
  float ltx = fmaxf(gx0, ax0), lty = fmaxf(gy0, ay0);
  float rbx = fminf(gx1, ax1), rby = fminf(gy1, ay1);
  float w = fmaxf(rbx - ltx, 0.0f), h = fmaxf(rby - lty, 0.0f);
  float inter = w * h;
  float uni = (garea + aarea) - inter;
  return inter / uni;
}

// inter/uni only (no division) — same rounding sequence as iou_pair's prefix.
__device__ __forceinline__ void iou_parts(float ax0, float ay0, float ax1, float ay1, float aarea,
                                          float gx0, float gy0, float gx1, float gy1, float garea,
                                          float& inter, float& uni) {
  #pragma clang fp contract(off)
  float ltx = fmaxf(gx0, ax0), lty = fmaxf(gy0, ay0);
  float rbx = fminf(gx1, ax1), rby = fminf(gy1, ay1);
  float w = fmaxf(rbx - ltx, 0.0f), h = fmaxf(rby - lty, 0.0f);
  inter = w * h;
  uni = (garea + aarea) - inter;
}

__device__ __forceinline__ void top4_insert(u64 (&top)[4], u64 key) {
  if (key > top[3]) {
    if (key > top[0])      { top[3]=top[2]; top[2]=top[1]; top[1]=top[0]; top[0]=key; }
    else if (key > top[1]) { top[3]=top[2]; top[2]=top[1]; top[1]=key; }
    else if (key > top[2]) { top[3]=top[2]; top[2]=key; }
    else                   { top[3]=key; }
  }
}

__device__ __forceinline__ void wave_merge_top4(u64 (&top)[4]) {
  for (int off = 32; off >= 1; off >>= 1) {
    u64 o[4];
    #pragma unroll
    for (int k = 0; k < 4; k++) o[k] = __shfl_down(top[k], (unsigned)off);
    u64 m[4]; int i = 0, j = 0;
    #pragma unroll
    for (int k = 0; k < 4; k++) m[k] = (top[i] >= o[j]) ? top[i++] : o[j++];
    #pragma unroll
    for (int k = 0; k < 4; k++) top[k] = m[k];
  }
}

__device__ __forceinline__ void wave_merge_top4_u32(u32 (&top)[4]) {
  for (int off = 32; off >= 1; off >>= 1) {
    u32 o[4];
    #pragma unroll
    for (int k = 0; k < 4; k++) o[k] = __shfl_down(top[k], (unsigned)off);
    u32 m[4]; int i = 0, j = 0;
    #pragma unroll
    for (int k = 0; k < 4; k++) m[k] = (top[i] >= o[j]) ? top[i++] : o[j++];
    #pragma unroll
    for (int k = 0; k < 4; k++) top[k] = m[k];
  }
}

// conservative screen threshold: t~ = bitcast(max(tau,8)-8)  (tau = f32 bits)
__device__ __forceinline__ float screen_thresh(u32 tau) {
  u32 tb = (tau > 8u) ? (tau - 8u) : 0u;
  return __uint_as_float(tb);
}

// ---------------- Kernel 0: sampled threshold pass ----------------
// grid (SUB_NS, B); block 512 = 8 waves; wave w handles gt-groups {2w, 2w+1}.
// Per (slice,gt): Q4 = 4th-largest of the 64 lane maxima of approx q. Raw Q4
// written to thr_part[b][s][gt]; k_main reduces with max over s.
__launch_bounds__(512, 4)
__global__ void k_thresh(const float4* __restrict__ anchors, const float4* __restrict__ gt,
                         u32* __restrict__ thr_part) {
  const int s = blockIdx.x;        // 0..SUB_NS-1, all full slices
  const int b = blockIdx.y;
  const int t = threadIdx.x;
  const int wave = t >> 6, lane = t & 63;

  __shared__ float4 sxy[AS];
  __shared__ float  sg[5][64];

  const int base = s * AS;
  const float4* ab = anchors + (size_t)b * A_N + base;

  for (int j = t; j < AS; j += 512) {
    float x0, y0, x1, y1, ar;
    conv_box(ab[j], x0, y0, x1, y1, ar);
    sxy[j] = make_float4(x0, y0, x1, y1);
  }
  if (t < 64) {
    float x0, y0, x1, y1, ar;
    conv_box(gt[(size_t)b * G_N + t], x0, y0, x1, y1, ar);
    sg[0][t] = x0; sg[1][t] = y0; sg[2][t] = x1; sg[3][t] = y1; sg[4][t] = ar;
  }
  __syncthreads();

  for (int gg = 0; gg < 2; gg++) {
    const int gi = (wave * 2 + gg) * 4;
    const float g0x0 = sg[0][gi],   g0y0 = sg[1][gi],   g0x1 = sg[2][gi],   g0y1 = sg[3][gi],   g0a = sg[4][gi];
    const float g1x0 = sg[0][gi+1], g1y0 = sg[1][gi+1], g1x1 = sg[2][gi+1], g1y1 = sg[3][gi+1], g1a = sg[4][gi+1];
    const float g2x0 = sg[0][gi+2], g2y0 = sg[1][gi+2], g2x1 = sg[2][gi+2], g2y1 = sg[3][gi+2], g2a = sg[4][gi+2];
    const float g3x0 = sg[0][gi+3], g3y0 = sg[1][gi+3], g3x1 = sg[2][gi+3], g3y1 = sg[3][gi+3], g3a = sg[4][gi+3];

    u32 q0 = 0, q1 = 0, q2 = 0, q3 = 0;
    for (int j = lane; j < AS; j += 64) {
      float4 x = sxy[j];
      float aarea = (x.z - x.x) * (x.w - x.y);
      float i0, u0, i1, u1, i2, u2, i3, u3;
      iou_parts(x.x, x.y, x.z, x.w, aarea, g0x0, g0y0, g0x1, g0y1, g0a, i0, u0);
      iou_parts(x.x, x.y, x.z, x.w, aarea, g1x0, g1y0, g1x1, g1y1, g1a, i1, u1);
      iou_parts(x.x, x.y, x.z, x.w, aarea, g2x0, g2y0, g2x1, g2y1, g2a, i2, u2);
      iou_parts(x.x, x.y, x.z, x.w, aarea, g3x0, g3y0, g3x1, g3y1, g3a, i3, u3);
      q0 = max(q0, __float_as_uint(i0 * __builtin_amdgcn_rcpf(u0)));
      q1 = max(q1, __float_as_uint(i1 * __builtin_amdgcn_rcpf(u1)));
      q2 = max(q2, __float_as_uint(i2 * __builtin_amdgcn_rcpf(u2)));
      q3 = max(q3, __float_as_uint(i3 * __builtin_amdgcn_rcpf(u3)));
    }
    u32 Q0[4] = {q0,0,0,0}, Q1[4] = {q1,0,0,0}, Q2[4] = {q2,0,0,0}, Q3[4] = {q3,0,0,0};
    wave_merge_top4_u32(Q0);
    wave_merge_top4_u32(Q1);
    wave_merge_top4_u32(Q2);
    wave_merge_top4_u32(Q3);
    if (lane == 0) {
      u32* dst = thr_part + ((size_t)b * SUB_NS + s) * G_N + gi;
      dst[0] = Q0[3]; dst[1] = Q1[3]; dst[2] = Q2[3]; dst[3] = Q3[3];
    }
  }
}

// ---------------- Kernel 1: screened exact pass (single pass over all pairs) ----------------
// grid (NS, B); block 512 = 8 waves; wave w handles gt-groups {2w, 2w+1}
// (so each wave's >=0.7 mask stays within one 32-gt half).
// launch_bounds (512,4): VGPR cap 128 — no spill (R8's (512,8) spilled).
__launch_bounds__(512, 4)
__global__ void k_main(const float4* __restrict__ anchors, const float4* __restrict__ gt,
                       const u32* __restrict__ thr_part,
                       u64* __restrict__ partial,
                       u64* __restrict__ posA, u64* __restrict__ posB) {
  const int s = blockIdx.x;
  const int b = blockIdx.y;
  const int t = threadIdx.x;
  const int wave = t >> 6, lane = t & 63;

  __shared__ float4 sxy[AS];        // converted xyxy; reused as wm after gp loop
  __shared__ float  sg[5][64];
  __shared__ float  sthr[64];       // per-gt screen thresholds (slack applied)
  u32* wm = (u32*)sxy;

  const int base = s * AS;
  const int acnt = min(AS, A_N - base);
  const float4* ab = anchors + (size_t)b * A_N + base;

  for (int j = t; j < acnt; j += 512) {
    float x0, y0, x1, y1, ar;
    conv_box(ab[j], x0, y0, x1, y1, ar);
    sxy[j] = make_float4(x0, y0, x1, y1);
  }
  if (t < 64) {
    float x0, y0, x1, y1, ar;
    conv_box(gt[(size_t)b * G_N + t], x0, y0, x1, y1, ar);
    sg[0][t] = x0; sg[1][t] = y0; sg[2][t] = x1; sg[3][t] = y1; sg[4][t] = ar;
    // global sampled threshold for gt t: max over the SUB_NS slice Q4s,
    // then the standard 16-ulp rcp slack + (0.7f - 8ulp) cap + 8-ulp margin.
    u32 mx = 0;
    for (int ss = 0; ss < SUB_NS; ss++)
      mx = max(mx, thr_part[((size_t)b * SUB_NS + ss) * G_N + t]);
    const u32 L7 = 0x3F333333u - 8u;   // 0.7f bits - 8 ulp
    sthr[t] = screen_thresh(min(mx > 16u ? mx - 16u : 0u, L7));
  }
  __syncthreads();

  u32 m = 0;   // bit k: anchor base+64k+lane has iou>=0.7 vs any of this wave's gts
  for (int gg = 0; gg < 2; gg++) {
    const int gp = wave * 2 + gg;      // 0..15
    const int gi = gp * 4;             // global gt index of group start
    const float g0x0 = sg[0][gi],   g0y0 = sg[1][gi],   g0x1 = sg[2][gi],   g0y1 = sg[3][gi],   g0a = sg[4][gi];
    const float g1x0 = sg[0][gi+1], g1y0 = sg[1][gi+1], g1x1 = sg[2][gi+1], g1y1 = sg[3][gi+1], g1a = sg[4][gi+1];
    const float g2x0 = sg[0][gi+2], g2y0 = sg[1][gi+2], g2x1 = sg[2][gi+2], g2y1 = sg[3][gi+2], g2a = sg[4][gi+2];
    const float g3x0 = sg[0][gi+3], g3y0 = sg[1][gi+3], g3x1 = sg[2][gi+3], g3y1 = sg[3][gi+3], g3a = sg[4][gi+3];
    const float t0 = sthr[gi], t1 = sthr[gi+1], t2 = sthr[gi+2], t3 = sthr[gi+3];

    // ---- single screened exact pass: top-4 + >=0.7 bits ----
    u64 T0[4] = {0,0,0,0}, T1[4] = {0,0,0,0}, T2[4] = {0,0,0,0}, T3[4] = {0,0,0,0};
    u32 h0 = 0, h1 = 0, h2 = 0, h3 = 0;
    u32 bit = 1u;
    for (int j = lane; j < acnt; j += 64, bit <<= 1) {
      float4 x = sxy[j];
      float aarea = (x.z - x.x) * (x.w - x.y);
      float i0, u0, i1, u1, i2, u2, i3, u3;
      iou_parts(x.x, x.y, x.z, x.w, aarea, g0x0, g0y0, g0x1, g0y1, g0a, i0, u0);
      iou_parts(x.x, x.y, x.z, x.w, aarea, g1x0, g1y0, g1x1, g1y1, g1a, i1, u1);
      iou_parts(x.x, x.y, x.z, x.w, aarea, g2x0, g2y0, g2x1, g2y1, g2a, i2, u2);
      iou_parts(x.x, x.y, x.z, x.w, aarea, g3x0, g3y0, g3x1, g3y1, g3a, i3, u3);
      u32 ni = ~(u32)(base + j);
      bool s0 = (i0 >= t0 * u0), s1 = (i1 >= t1 * u1);
      bool s2 = (i2 >= t2 * u2), s3 = (i3 >= t3 * u3);
      if (__ballot(s0)) {
        float v = 0.0f;
        if (s0) { v = i0 / u0; if (v >= 0.7f) m |= bit; }
        u32 vb = __float_as_uint(v);
        bool ins = s0 && (vb >= h0);
        if (__ballot(ins)) {
          if (ins) top4_insert(T0, ((u64)vb << 32) | (u64)ni);
          h0 = (u32)(T0[3] >> 32);
        }
      }
      if (__ballot(s1)) {
        float v = 0.0f;
        if (s1) { v = i1 / u1; if (v >= 0.7f) m |= bit; }
        u32 vb = __float_as_uint(v);
        bool ins = s1 && (vb >= h1);
        if (__ballot(ins)) {
          if (ins) top4_insert(T1, ((u64)vb << 32) | (u64)ni);
          h1 = (u32)(T1[3] >> 32);
        }
      }
      if (__ballot(s2)) {
        float v = 0.0f;
        if (s2) { v = i2 / u2; if (v >= 0.7f) m |= bit; }
        u32 vb = __float_as_uint(v);
        bool ins = s2 && (vb >= h2);
        if (__ballot(ins)) {
          if (ins) top4_insert(T2, ((u64)vb << 32) | (u64)ni);
          h2 = (u32)(T2[3] >> 32);
        }
      }
      if (__ballot(s3)) {
        float v = 0.0f;
        if (s3) { v = i3 / u3; if (v >= 0.7f) m |= bit; }
        u32 vb = __float_as_uint(v);
        bool ins = s3 && (vb >= h3);
        if (__ballot(ins)) {
          if (ins) top4_insert(T3, ((u64)vb << 32) | (u64)ni);
          h3 = (u32)(T3[3] >> 32);
        }
      }
    }
    wave_merge_top4(T0);
    wave_merge_top4(T1);
    wave_merge_top4(T2);
    wave_merge_top4(T3);
    if (lane == 0) {
      u64* dst = partial + (((size_t)b * NS + s) * G_N + gi) * 4;
      #pragma unroll
      for (int k = 0; k < 4; k++) {
        dst[k] = T0[k]; dst[4 + k] = T1[k]; dst[8 + k] = T2[k]; dst[12 + k] = T3[k];
      }
    }
  }

  __syncthreads();      // all waves done reading sxy (wm aliases it)
  wm[t] = m;
  __syncthreads();
  // waves 0-3 (threads 0..255) handled gts 0..31 -> posA; waves 4-7 -> posB.
  if (wave == 0 || wave == 4) {
    const u32* wmh = wm + (wave & 4) * 64;
    u32 mc = wmh[lane] | wmh[64 + lane] | wmh[128 + lane] | wmh[192 + lane];
    u64* posH = (wave ? posB : posA) + (size_t)b * NWORD + s * WPS;
    for (int k = 0; k < WPS; k++) {
      u64 bal = __ballot((mc >> k) & 1u);
      if (lane == 0) posH[k] = bal;    // plain store — every word covered exactly once
    }
  }
}

// ---------------- Kernel 2: merge partials -> top4; lq anchors -> posA ----------------
__launch_bounds__(64)
__global__ void k_top4_merge(const u64* __restrict__ partial, u64* __restrict__ top4,
                             u64* __restrict__ posA) {
  const int b = blockIdx.y, g = blockIdx.x, lane = threadIdx.x;
  const u64* pb = partial + ((size_t)b * NS * G_N + g) * 4;
  u64 keys[7];                       // NS*4 = 392 -> <= 7 per lane
  int nk = 0;
  for (int i = lane; i < NS * 4; i += 64)
    keys[nk++] = pb[(size_t)(i >> 2) * (G_N * 4) + (i & 3)];
  u64 top[4] = {0ull, 0ull, 0ull, 0ull};
  for (int q = 0; q < nk; q++) top4_insert(top, keys[q]);
  wave_merge_top4(top);
  if (lane == 0) {
    u64* dst = top4 + ((size_t)b * G_N + g) * 4;
    #pragma unroll
    for (int k = 0; k < 4; k++) dst[k] = top[k];
  }
  // low-quality matches: every partial entry whose value bits == hq bits.
  u32 hqb = (u32)(__shfl(top[0], 0) >> 32);
  for (int q = 0; q < nk; q++) {
    u64 key = keys[q];
    u32 aidx = ~(u32)key;
    if ((u32)(key >> 32) == hqb && aidx < A_N)
      atomicOr(&posA[(size_t)b * NWORD + (aidx >> 6)], 1ull << (aidx & 63));
  }
}

// ---------------- Kernel 3: fused per-image tail ----------------
// grid (B) = 8 blocks x 1024 threads. All per-image scalar state in LDS.
// Phases (verbatim ports of the R11 kernels, sequenced by __syncthreads):
//   1. hist + npos from pos bits (threefry per pos anchor)
//   2. bin select (once per image)
//   3. collect fine candidates of selected bin into LDS
//   4. Tstar binary search (wave 0)
//   5. compact selected anchors (provably <=128) into LDS list
//   6. 64-gt argmax per selected anchor -> cnt
//   7. write the 4 output streams (reads top4 written by k_top4_merge)
__launch_bounds__(1024, 4)
__global__ void k_final(const float4* __restrict__ anchors, const float4* __restrict__ gt,
                        const u64* __restrict__ top4,
                        const u64* __restrict__ posA, const u64* __restrict__ posB,
                        float* __restrict__ out, int sec) {
  const int b = blockIdx.x;
  const int t = threadIdx.x;
  const int wave = t >> 6, lane = t & 63;

  __shared__ u32  shist[4096];       // 16 KB rand-bits histogram
  __shared__ u32  sfine[FINE_CAP];   // 16 KB fine candidates of selected bin
  __shared__ float sg[5][G_N];       // gt boxes (xyxy + area)
  __shared__ u32  red[256];          // coarse hist sums
  __shared__ u32  ssel[256];         // selected anchors (<=128 + safety)
  __shared__ u32  scnt[G_N];         // selected count per gt
  __shared__ u32  snpos, sfcnt, sselc;
  __shared__ int  sbin, sbefore;
  __shared__ u64  sT;

  for (int i = t; i < 4096; i += 1024) shist[i] = 0;
  if (t < G_N) scnt[t] = 0;
  if (t == 0) { snpos = 0; sfcnt = 0; sselc = 0; }
  if (t < G_N) {
    float x0, y0, x1, y1, ar;
    conv_box(gt[(size_t)b * G_N + t], x0, y0, x1, y1, ar);
    sg[0][t] = x0; sg[1][t] = y0; sg[2][t] = x1; sg[3][t] = y1; sg[4][t] = ar;
  }
  __syncthreads();

  // ---- phase 1: npos + hist ----
  u32 k0, k1; image_key(b, k0, k1);
  const u64* pa = posA + (size_t)b * NWORD;
  const u64* pbw = posB + (size_t)b * NWORD;
  for (int i = t; i < NWORD; i += 1024) {
    u64 w = pa[i] | pbw[i];
    if (w) {
      atomicAdd(&snpos, (u32)__popcll(w));
      while (w) {
        int bit = __ffsll((long long)w) - 1; w &= w - 1;
        u32 a = (u32)(i * 64 + bit);
        atomicAdd(&shist[rbits_for(k0, k1, a) >> 20], 1u);
      }
    }
  }
  __syncthreads();

  // ---- phase 2: bin select (identical logic to R11 k_collect head) ----
  if (t < 256) {
    u32 local = 0;
    for (int j = 0; j < 16; j++) local += shist[t * 16 + j];
    red[t] = local;
  }
  __syncthreads();
  if (t == 0) {
    if (snpos <= MAX_POS) {
      sbin = -1; sbefore = 0;
    } else {
      u32 cum = 0; int chunk = 0;
      for (int i = 0; i < 256; i++) {
        if (cum + red[i] >= MAX_POS) { chunk = i; break; }
        cum += red[i];
      }
      int tb = chunk * 16; u32 before = cum;
      for (int j = 0; j < 16; j++) {
        u32 h = shist[chunk * 16 + j];
        if (before + h >= MAX_POS) { tb = chunk * 16 + j; break; }
        before += h;
      }
      sbin = tb; sbefore = (int)before;
    }
  }
  __syncthreads();

  // ---- phase 3: collect fine candidates of the selected bin ----
  if (sbin >= 0) {
    const int stb = sbin;
    for (int i = t; i < NWORD; i += 1024) {
      u64 w = pa[i] | pbw[i];
      while (w) {
        int bit = __ffsll((long long)w) - 1; w &= w - 1;
        u32 a = (u32)(i * 64 + bit);
        u32 rb = rbits_for(k0, k1, a);
        if ((int)(rb >> 20) != stb) continue;
        u32 idx = atomicAdd(&sfcnt, 1u);
        if (idx < FINE_CAP) sfine[idx] = (((rb >> 9) & 0x7FFu) << 18) | a;
      }
    }
  }
  __syncthreads();

  // ---- phase 4: Tstar binary search (wave 0; identical to R11 k_count head) ----
  if (wave == 0) {
    u64 T = ~0ull;
    if (sbin >= 0) {
      const int m = min((int)sfcnt, FINE_CAP);
      const u32 need = (u32)(MAX_POS - sbefore);   // >= 1
      u32 lo = 0, hi = (1u << 29) - 1;
      while (lo < hi) {
        u32 mid = lo + ((hi - lo) >> 1);
        u32 c = 0;
        for (int j = lane; j < m; j += 64) c += (sfine[j] <= mid) ? 1u : 0u;
        #pragma unroll
        for (int off = 32; off >= 1; off >>= 1) c += __shfl_xor(c, off);
        if (c >= need) hi = mid; else lo = mid + 1;   // uniform across wave
      }
      T = ((u64)(u32)sbin << 29) | (u64)lo;   // 41-bit threshold
    }
    if (lane == 0) sT = T;
  }
  __syncthreads();

  // ---- phase 5: compact selected anchors (identical predicate to R11 k_count) ----
  const u64 T = sT;
  for (int i = t; i < NWORD; i += 1024) {
    u64 w = pa[i] | pbw[i];
    while (w) {
      int bit = __ffsll((long long)w) - 1; w &= w - 1;
      u32 a = (u32)(i * 64 + bit);
      if (T != ~0ull) {
        u32 rb = rbits_for(k0, k1, a);
        if (((((u64)(rb >> 9)) << 18) | (u64)a) > T) continue;
      }
      u32 idx = atomicAdd(&sselc, 1u);
      if (idx < 256) ssel[idx] = a;
    }
  }
  __syncthreads();

  // ---- phase 6: per-selected-anchor 64-gt argmax -> cnt ----
  const float4* ab = anchors + (size_t)b * A_N;
  {
    const int ns = min((int)sselc, 256);
    if (t < ns) {
      u32 a = ssel[t];
      float ax0, ay0, ax1, ay1, aar;
      conv_box(ab[a], ax0, ay0, ax1, ay1, aar);
      float bv = -1.0f; int g0 = 0;
      for (int g = 0; g < 64; g++) {
        float v = iou_pair(ax0, ay0, ax1, ay1, aar,
                           sg[0][g], sg[1][g], sg[2][g], sg[3][g], sg[4][g]);
        if (v > bv) { bv = v; g0 = g; }   // strict > = first max (jnp.argmax)
      }
      atomicAdd(&scnt[g0], 1u);
    }
  }
  __syncthreads();

  // ---- phase 7: output (identical to R11 k_out) ----
  if (t < G_N) {
    const int g = t;
    const u32 c = min(scnt[g], (u32)K_TOP);
    const u64* t4 = top4 + ((size_t)b * G_N + g) * 4;
    #pragma unroll
    for (int k = 0; k < 4; k++) {
      u64 key = t4[k];
      u32 fb = (u32)(key >> 32);
      u32 aidx = ~(u32)key;
      bool valid = (u32)k < c;
      int o = b * (G_N * K_TOP) + g * K_TOP + k;
      out[0 * sec + o] = valid ? (float)aidx : -1.0f;          // pr_inds
      out[1 * sec + o] = valid ? (float)g : -1.0f;             // gt_inds
      out[2 * sec + o] = valid ? 1.0f : 0.0f;                  // valid mask
      out[3 * sec + o] = valid ? __uint_as_float(fb) : 0.0f;   // topk ious
    }
  }
}

extern "C" void kernel_launch(void* const* d_in, const int* in_sizes, int n_in,
                              void* d_out, int out_size, void* d_ws, size_t ws_size,
                              hipStream_t stream) {
  const float4* anchors = (const float4*)d_in[0];  // [B, A, 4] cxcywh
  const float4* gt      = (const float4*)d_in[1];  // [B, G, 4] cxcywh
  float* out = (float*)d_out;                      // 4 x [B, G*K] concatenated

  // Layout — IDENTICAL EXTENT to the R5..R11-proven 2,025,536 B:
  //   top4    @ 0          (16,384)
  //     alias: thr_part @ 0 (8*8*64*4 = 16,384) [written k_thresh, read k_main,
  //            dead once k_top4_merge overwrites top4]
  //   partial @ 16,384     (8*98*64*32 = 1,605,632) — dead after k_top4_merge
  //   posA    @ 1,622,016  (200,704)  [fully ballot-stored — no init]
  //   posB    @ 1,822,720  (200,704)  [fully ballot-stored — no init]
  // hist/fine/binsel/npos/fcnt/cnt now live in k_final's LDS.
  char* ws = (char*)d_ws;
  u64*  top4    = (u64*)(ws);
  u32*  thr_prt = (u32*)(ws);
  u64*  partial = (u64*)(ws + 16384);
  u64*  posA    = (u64*)(ws + 1622016);
  u64*  posB    = (u64*)(ws + 1822720);

  int sec = out_size / 4;  // 2048 = B*G*K

  k_thresh    <<<dim3(SUB_NS, B_IMG), 512, 0, stream>>>(anchors, gt, thr_prt);
  k_main      <<<dim3(NS, B_IMG), 512, 0, stream>>>(anchors, gt, thr_prt, partial, posA, posB);
  k_top4_merge<<<dim3(G_N, B_IMG), 64, 0, stream>>>(partial, top4, posA);
  k_final     <<<dim3(B_IMG), 1024, 0, stream>>>(anchors, gt, top4, posA, posB, out, sec);
}

// Round 6
// 270.624 us; speedup vs baseline: 1.0550x; 1.0550x over previous
//
#include <hip/hip_runtime.h>
#include <stdint.h>

// Stage1Assigner (RPN matcher + subsample + top-k per GT) for MI355X.
// B=8 images, A=200000 anchors, G=64 GTs, K=4, thresholds 0.3/0.7, 128 max pos.
//
// PRNG: JAX threefry, jax_threefry_partitionable=True:
//   keys[b] = threefry2x32((0,42),(0,b));  bits[a] = y0^y1 of threefry2x32(key_b,(0,a))
// Selection of 128 positives = 128 lexicographically smallest (bits>>9, a).
//
// R13 vs R12/R11 (counter-driven): R10/R12 proved that per-image phases run at
// 8-block parallelism are latency-bound and slow (k_tail 213us @ VALUBusy 2%;
// k_final ate all dispatch savings). R13 reverts to the R11-proven WIDE tail
// and instead absorbs the two bookkeeping dispatches into wide kernels:
//   * k_zero -> k_thresh (64 blocks x 512 thr = 32768 = one hist word each).
//   * k_hist -> k_main (+ k_top4_merge): k_main's ballot phase now ORs all 8
//     wave masks into ONE pos bitmap (posB eliminated -> frees 200KB, giving
//     the hist a home UNDER the proven 2,025,536B workspace cap), pops its
//     ~13 bits/slice and does threefry+hist atomicAdd + npos there (trivial);
//     k_top4_merge hists only NEWLY-set lq bits (atomicOr old-value dedup).
//     npos = sum of popcounts = exact pos-set size, same as old k_hist.
//   * k_main: 4 survivor ballots gated by one combined ballot (survivor
//     events ~0.4%/iter -> common path drops 3 ballots + 3 branches).
// 8 dispatches -> 6. All exact comparisons identical to R5..R12 ->
// bit-identical output.
//
// Screen (R11, proven): thrG[gt] = max over 8 sampled slices of the
// 4th-of-lane-maxima of approx q = inter*rcp(uni); sample-4th <= global-4th.
//   t~ = bits(min(thrG - 16ulp, 0.7f - 8ulp)) - 8ulp  (rcp err <= ~2.5 ulp
//   << 16-ulp slack; 8-ulp product margin covers binade edges; denormal
//   flush -> never-skip; thrG=0 -> screen passes everything -> safe).
// Value-0 fake entries (masked lanes insert vb=0 early) are displaced whenever
// a gt has >=4 anchors with iou>0 globally (guaranteed for uniform boxes).
//
// IoU is fp-contract(off) IEEE per-op: identical bits across all passes and
// matches XLA per-HLO rounding.

#pragma clang fp contract(off)

#define B_IMG 8
#define A_N 200000
#define G_N 64
#define K_TOP 4
#define MAX_POS 128
#define FINE_CAP 4096
#define AS 2048
#define NS 98            // ceil(200000/2048)
#define SUB_NS 8         // sampled slices for the threshold pass
#define WPS 32           // u64 ballot words per slice
#define NWORD 3136       // NS*WPS words of pos bits per image

typedef unsigned long long u64;
typedef unsigned int u32;

__device__ __forceinline__ u32 rotl32(u32 v, int n) { return (v << n) | (v >> (32 - n)); }

__device__ __forceinline__ void tf_round(u32& x0, u32& x1, int r) {
  x0 += x1; x1 = rotl32(x1, r); x1 ^= x0;
}

__device__ __forceinline__ void threefry2x32(u32 k0, u32 k1, u32& x0, u32& x1) {
  u32 ks2 = 0x1BD11BDAu ^ k0 ^ k1;
  x0 += k0; x1 += k1;
  tf_round(x0,x1,13); tf_round(x0,x1,15); tf_round(x0,x1,26); tf_round(x0,x1,6);
  x0 += k1; x1 += ks2 + 1u;
  tf_round(x0,x1,17); tf_round(x0,x1,29); tf_round(x0,x1,16); tf_round(x0,x1,24);
  x0 += ks2; x1 += k0 + 2u;
  tf_round(x0,x1,13); tf_round(x0,x1,15); tf_round(x0,x1,26); tf_round(x0,x1,6);
  x0 += k0; x1 += k1 + 3u;
  tf_round(x0,x1,17); tf_round(x0,x1,29); tf_round(x0,x1,16); tf_round(x0,x1,24);
  x0 += k1; x1 += ks2 + 4u;
  tf_round(x0,x1,13); tf_round(x0,x1,15); tf_round(x0,x1,26); tf_round(x0,x1,6);
  x0 += ks2; x1 += k0 + 5u;
}

__device__ __forceinline__ void image_key(int b, u32& kb0, u32& kb1) {
  u32 x0 = 0u, x1 = (u32)b;
  threefry2x32(0u, 42u, x0, x1);
  kb0 = x0; kb1 = x1;
}

__device__ __forceinline__ u32 rbits_for(u32 k0, u32 k1, u32 a) {
  u32 x0 = 0u, x1 = a;
  threefry2x32(k0, k1, x0, x1);
  return x0 ^ x1;
}

__device__ __forceinline__ void conv_box(float4 bx, float& x0, float& y0,
                                         float& x1, float& y1, float& area) {
  #pragma clang fp contract(off)
  x0 = bx.x - 0.5f * bx.z;
  y0 = bx.y - 0.5f * bx.w;
  x1 = bx.x + 0.5f * bx.z;
  y1 = bx.y + 0.5f * bx.w;
  area = (x1 - x0) * (y1 - y0);
}

__device__ __forceinline__ float iou_pair(float ax0, float ay0, float ax1, float ay1, float aarea,
                                          float gx0, float gy0, float gx1, float gy1, float garea) {
  #pragma clang fp contract(off)
  float ltx = fmaxf(gx0, ax0), lty = fmaxf(gy0, ay0);
  float rbx = fminf(gx1, ax1), rby = fminf(gy1, ay1);
  float w = fmaxf(rbx - ltx, 0.0f), h = fmaxf(rby - lty, 0.0f);
  float inter = w * h;
  float uni = (garea + aarea) - inter;
  return inter / uni;
}

// inter/uni only (no division) — same rounding sequence as iou_pair's prefix.
__device__ __forceinline__ void iou_parts(float ax0, float ay0, float ax1, float ay1, float aarea,
                                          float gx0, float gy0, float gx1, float gy1, float garea,
                                          float& inter, float& uni) {
  #pragma clang fp contract(off)
  float ltx = fmaxf(gx0, ax0), lty = fmaxf(gy0, ay0);
  float rbx = fminf(gx1, ax1), rby = fminf(gy1, ay1);
  float w = fmaxf(rbx - ltx, 0.0f), h = fmaxf(rby - lty, 0.0f);
  inter = w * h;
  uni = (garea + aarea) - inter;
}

__device__ __forceinline__ void top4_insert(u64 (&top)[4], u64 key) {
  if (key > top[3]) {
    if (key > top[0])      { top[3]=top[2]; top[2]=top[1]; top[1]=top[0]; top[0]=key; }
    else if (key > top[1]) { top[3]=top[2]; top[2]=top[1]; top[1]=key; }
    else if (key > top[2]) { top[3]=top[2]; top[2]=key; }
    else                   { top[3]=key; }
  }
}

__device__ __forceinline__ void wave_merge_top4(u64 (&top)[4]) {
  for (int off = 32; off >= 1; off >>= 1) {
    u64 o[4];
    #pragma unroll
    for (int k = 0; k < 4; k++) o[k] = __shfl_down(top[k], (unsigned)off);
    u64 m[4]; int i = 0, j = 0;
    #pragma unroll
    for (int k = 0; k < 4; k++) m[k] = (top[i] >= o[j]) ? top[i++] : o[j++];
    #pragma unroll
    for (int k = 0; k < 4; k++) top[k] = m[k];
  }
}

__device__ __forceinline__ void wave_merge_top4_u32(u32 (&top)[4]) {
  for (int off = 32; off >= 1; off >>= 1) {
    u32 o[4];
    #pragma unroll
    for (int k = 0; k < 4; k++) o[k] = __shfl_down(top[k], (unsigned)off);
    u32 m[4]; int i = 0, j = 0;
    #pragma unroll
    for (int k = 0; k < 4; k++) m[k] = (top[i] >= o[j]) ? top[i++] : o[j++];
    #pragma unroll
    for (int k = 0; k < 4; k++) top[k] = m[k];
  }
}

// conservative screen threshold: t~ = bitcast(max(tau,8)-8)  (tau = f32 bits)
__device__ __forceinline__ float screen_thresh(u32 tau) {
  u32 tb = (tau > 8u) ? (tau - 8u) : 0u;
  return __uint_as_float(tb);
}

// ---------------- Kernel 0: sampled threshold pass (+ zero hist & small state) ----------------
// grid (SUB_NS, B); block 512 = 8 waves; wave w handles gt-groups {2w, 2w+1}.
// Per (slice,gt): Q4 = 4th-largest of the 64 lane maxima of approx q. Raw Q4
// written to thr_part[b][s][gt]; k_main reduces with max over s.
// 64 blocks x 512 threads = 32768 = exactly one hist word each (zeroing).
__launch_bounds__(512, 4)
__global__ void k_thresh(const float4* __restrict__ anchors, const float4* __restrict__ gt,
                         u32* __restrict__ thr_part, u32* __restrict__ hist,
                         u32* __restrict__ npos, u32* __restrict__ fcnt,
                         u32* __restrict__ cnt) {
  const int s = blockIdx.x;        // 0..SUB_NS-1, all full slices
  const int b = blockIdx.y;
  const int t = threadIdx.x;
  const int wave = t >> 6, lane = t & 63;

  __shared__ float4 sxy[AS];
  __shared__ float  sg[5][64];

  // zero hist: one word per thread across the whole grid
  hist[(b * SUB_NS + s) * 512 + t] = 0;
  if (s == 0) {
    if (t < 64) cnt[b * G_N + t] = 0;
    if (t == 0) { fcnt[b] = 0; npos[b] = 0; }
  }

  const int base = s * AS;
  const float4* ab = anchors + (size_t)b * A_N + base;

  for (int j = t; j < AS; j += 512) {
    float x0, y0, x1, y1, ar;
    conv_box(ab[j], x0, y0, x1, y1, ar);
    sxy[j] = make_float4(x0, y0, x1, y1);
  }
  if (t < 64) {
    float x0, y0, x1, y1, ar;
    conv_box(gt[(size_t)b * G_N + t], x0, y0, x1, y1, ar);
    sg[0][t] = x0; sg[1][t] = y0; sg[2][t] = x1; sg[3][t] = y1; sg[4][t] = ar;
  }
  __syncthreads();

  for (int gg = 0; gg < 2; gg++) {
    const int gi = (wave * 2 + gg) * 4;
    const float g0x0 = sg[0][gi],   g0y0 = sg[1][gi],   g0x1 = sg[2][gi],   g0y1 = sg[3][gi],   g0a = sg[4][gi];
    const float g1x0 = sg[0][gi+1], g1y0 = sg[1][gi+1], g1x1 = sg[2][gi+1], g1y1 = sg[3][gi+1], g1a = sg[4][gi+1];
    const float g2x0 = sg[0][gi+2], g2y0 = sg[1][gi+2], g2x1 = sg[2][gi+2], g2y1 = sg[3][gi+2], g2a = sg[4][gi+2];
    const float g3x0 = sg[0][gi+3], g3y0 = sg[1][gi+3], g3x1 = sg[2][gi+3], g3y1 = sg[3][gi+3], g3a = sg[4][gi+3];

    u32 q0 = 0, q1 = 0, q2 = 0, q3 = 0;
    for (int j = lane; j < AS; j += 64) {
      float4 x = sxy[j];
      float aarea = (x.z - x.x) * (x.w - x.y);
      float i0, u0, i1, u1, i2, u2, i3, u3;
      iou_parts(x.x, x.y, x.z, x.w, aarea, g0x0, g0y0, g0x1, g0y1, g0a, i0, u0);
      iou_parts(x.x, x.y, x.z, x.w, aarea, g1x0, g1y0, g1x1, g1y1, g1a, i1, u1);
      iou_parts(x.x, x.y, x.z, x.w, aarea, g2x0, g2y0, g2x1, g2y1, g2a, i2, u2);
      iou_parts(x.x, x.y, x.z, x.w, aarea, g3x0, g3y0, g3x1, g3y1, g3a, i3, u3);
      q0 = max(q0, __float_as_uint(i0 * __builtin_amdgcn_rcpf(u0)));
      q1 = max(q1, __float_as_uint(i1 * __builtin_amdgcn_rcpf(u1)));
      q2 = max(q2, __float_as_uint(i2 * __builtin_amdgcn_rcpf(u2)));
      q3 = max(q3, __float_as_uint(i3 * __builtin_amdgcn_rcpf(u3)));
    }
    u32 Q0[4] = {q0,0,0,0}, Q1[4] = {q1,0,0,0}, Q2[4] = {q2,0,0,0}, Q3[4] = {q3,0,0,0};
    wave_merge_top4_u32(Q0);
    wave_merge_top4_u32(Q1);
    wave_merge_top4_u32(Q2);
    wave_merge_top4_u32(Q3);
    if (lane == 0) {
      u32* dst = thr_part + ((size_t)b * SUB_NS + s) * G_N + gi;
      dst[0] = Q0[3]; dst[1] = Q1[3]; dst[2] = Q2[3]; dst[3] = Q3[3];
    }
  }
}

// ---------------- Kernel 1: screened exact pass + pos bitmap + hist ----------------
// grid (NS, B); block 512 = 8 waves; wave w handles gt-groups {2w, 2w+1}.
// Ballot phase ORs ALL 8 wave masks -> ONE pos bitmap (posA); wave 0 pops its
// bits, threefry-hists them and bumps npos (dedup across gts inherent in OR).
// launch_bounds (512,4): VGPR cap 128 — no spill (R8's (512,8) spilled).
__launch_bounds__(512, 4)
__global__ void k_main(const float4* __restrict__ anchors, const float4* __restrict__ gt,
                       const u32* __restrict__ thr_part,
                       u64* __restrict__ partial, u64* __restrict__ posA,
                       u32* __restrict__ hist, u32* __restrict__ npos) {
  const int s = blockIdx.x;
  const int b = blockIdx.y;
  const int t = threadIdx.x;
  const int wave = t >> 6, lane = t & 63;

  __shared__ float4 sxy[AS];        // converted xyxy; reused as wm after gp loop
  __shared__ float  sg[5][64];
  __shared__ float  sthr[64];       // per-gt screen thresholds (slack applied)
  u32* wm = (u32*)sxy;

  const int base = s * AS;
  const int acnt = min(AS, A_N - base);
  const float4* ab = anchors + (size_t)b * A_N + base;

  for (int j = t; j < acnt; j += 512) {
    float x0, y0, x1, y1, ar;
    conv_box(ab[j], x0, y0, x1, y1, ar);
    sxy[j] = make_float4(x0, y0, x1, y1);
  }
  if (t < 64) {
    float x0, y0, x1, y1, ar;
    conv_box(gt[(size_t)b * G_N + t], x0, y0, x1, y1, ar);
    sg[0][t] = x0; sg[1][t] = y0; sg[2][t] = x1; sg[3][t] = y1; sg[4][t] = ar;
    // global sampled threshold for gt t: max over the SUB_NS slice Q4s,
    // then the standard 16-ulp rcp slack + (0.7f - 8ulp) cap + 8-ulp margin.
    u32 mx = 0;
    for (int ss = 0; ss < SUB_NS; ss++)
      mx = max(mx, thr_part[((size_t)b * SUB_NS + ss) * G_N + t]);
    const u32 L7 = 0x3F333333u - 8u;   // 0.7f bits - 8 ulp
    sthr[t] = screen_thresh(min(mx > 16u ? mx - 16u : 0u, L7));
  }
  __syncthreads();

  u32 m = 0;   // bit k: anchor base+64k+lane has iou>=0.7 vs any of this wave's gts
  for (int gg = 0; gg < 2; gg++) {
    const int gp = wave * 2 + gg;      // 0..15
    const int gi = gp * 4;             // global gt index of group start
    const float g0x0 = sg[0][gi],   g0y0 = sg[1][gi],   g0x1 = sg[2][gi],   g0y1 = sg[3][gi],   g0a = sg[4][gi];
    const float g1x0 = sg[0][gi+1], g1y0 = sg[1][gi+1], g1x1 = sg[2][gi+1], g1y1 = sg[3][gi+1], g1a = sg[4][gi+1];
    const float g2x0 = sg[0][gi+2], g2y0 = sg[1][gi+2], g2x1 = sg[2][gi+2], g2y1 = sg[3][gi+2], g2a = sg[4][gi+2];
    const float g3x0 = sg[0][gi+3], g3y0 = sg[1][gi+3], g3x1 = sg[2][gi+3], g3y1 = sg[3][gi+3], g3a = sg[4][gi+3];
    const float t0 = sthr[gi], t1 = sthr[gi+1], t2 = sthr[gi+2], t3 = sthr[gi+3];

    // ---- single screened exact pass: top-4 + >=0.7 bits ----
    u64 T0[4] = {0,0,0,0}, T1[4] = {0,0,0,0}, T2[4] = {0,0,0,0}, T3[4] = {0,0,0,0};
    u32 h0 = 0, h1 = 0, h2 = 0, h3 = 0;
    u32 bit = 1u;
    for (int j = lane; j < acnt; j += 64, bit <<= 1) {
      float4 x = sxy[j];
      float aarea = (x.z - x.x) * (x.w - x.y);
      float i0, u0, i1, u1, i2, u2, i3, u3;
      iou_parts(x.x, x.y, x.z, x.w, aarea, g0x0, g0y0, g0x1, g0y1, g0a, i0, u0);
      iou_parts(x.x, x.y, x.z, x.w, aarea, g1x0, g1y0, g1x1, g1y1, g1a, i1, u1);
      iou_parts(x.x, x.y, x.z, x.w, aarea, g2x0, g2y0, g2x1, g2y1, g2a, i2, u2);
      iou_parts(x.x, x.y, x.z, x.w, aarea, g3x0, g3y0, g3x1, g3y1, g3a, i3, u3);
      bool s0 = (i0 >= t0 * u0), s1 = (i1 >= t1 * u1);
      bool s2 = (i2 >= t2 * u2), s3 = (i3 >= t3 * u3);
      // combined gate: survivor events are rare (~0.4%/iter) — one ballot
      // covers the common path; inner ballots/bodies identical to R11.
      if (__ballot(s0 || s1 || s2 || s3)) {
        u32 ni = ~(u32)(base + j);
        if (__ballot(s0)) {
          float v = 0.0f;
          if (s0) { v = i0 / u0; if (v >= 0.7f) m |= bit; }
          u32 vb = __float_as_uint(v);
          bool ins = s0 && (vb >= h0);
          if (__ballot(ins)) {
            if (ins) top4_insert(T0, ((u64)vb << 32) | (u64)ni);
            h0 = (u32)(T0[3] >> 32);
          }
        }
        if (__ballot(s1)) {
          float v = 0.0f;
          if (s1) { v = i1 / u1; if (v >= 0.7f) m |= bit; }
          u32 vb = __float_as_uint(v);
          bool ins = s1 && (vb >= h1);
          if (__ballot(ins)) {
            if (ins) top4_insert(T1, ((u64)vb << 32) | (u64)ni);
            h1 = (u32)(T1[3] >> 32);
          }
        }
        if (__ballot(s2)) {
          float v = 0.0f;
          if (s2) { v = i2 / u2; if (v >= 0.7f) m |= bit; }
          u32 vb = __float_as_uint(v);
          bool ins = s2 && (vb >= h2);
          if (__ballot(ins)) {
            if (ins) top4_insert(T2, ((u64)vb << 32) | (u64)ni);
            h2 = (u32)(T2[3] >> 32);
          }
        }
        if (__ballot(s3)) {
          float v = 0.0f;
          if (s3) { v = i3 / u3; if (v >= 0.7f) m |= bit; }
          u32 vb = __float_as_uint(v);
          bool ins = s3 && (vb >= h3);
          if (__ballot(ins)) {
            if (ins) top4_insert(T3, ((u64)vb << 32) | (u64)ni);
            h3 = (u32)(T3[3] >> 32);
          }
        }
      }
    }
    wave_merge_top4(T0);
    wave_merge_top4(T1);
    wave_merge_top4(T2);
    wave_merge_top4(T3);
    if (lane == 0) {
      u64* dst = partial + (((size_t)b * NS + s) * G_N + gi) * 4;
      #pragma unroll
      for (int k = 0; k < 4; k++) {
        dst[k] = T0[k]; dst[4 + k] = T1[k]; dst[8 + k] = T2[k]; dst[12 + k] = T3[k];
      }
    }
  }

  __syncthreads();      // all waves done reading sxy (wm aliases it)
  wm[t] = m;
  __syncthreads();
  // wave 0: full OR over all 8 wave masks -> one pos bitmap; pop bits for
  // hist + npos (dedup across gts inherent in the OR).
  if (wave == 0) {
    u32 mc = 0;
    #pragma unroll
    for (int w = 0; w < 8; w++) mc |= wm[w * 64 + lane];
    u64* posH = posA + (size_t)b * NWORD + s * WPS;
    for (int k = 0; k < WPS; k++) {
      u64 bal = __ballot((mc >> k) & 1u);
      if (lane == 0) posH[k] = bal;    // plain store — every word covered exactly once
    }
    // hist + npos for this slice's pos anchors
    u32 k0, k1; image_key(b, k0, k1);
    u32 c = (u32)__popc(mc);
    u32 mm = mc;
    while (mm) {
      int k = __ffs((int)mm) - 1; mm &= mm - 1;
      u32 a = (u32)(base + k * 64 + lane);
      atomicAdd(&hist[b * 4096 + (rbits_for(k0, k1, a) >> 20)], 1u);
    }
    #pragma unroll
    for (int off = 32; off >= 1; off >>= 1) c += __shfl_xor(c, off);
    if (lane == 0 && c) atomicAdd(&npos[b], c);
  }
}

// ---------------- Kernel 2: merge partials -> top4; lq anchors -> posA (+hist) ----------------
__launch_bounds__(64)
__global__ void k_top4_merge(const u64* __restrict__ partial, u64* __restrict__ top4,
                             u64* __restrict__ posA,
                             u32* __restrict__ hist, u32* __restrict__ npos) {
  const int b = blockIdx.y, g = blockIdx.x, lane = threadIdx.x;
  const u64* pb = partial + ((size_t)b * NS * G_N + g) * 4;
  u64 keys[7];                       // NS*4 = 392 -> <= 7 per lane
  int nk = 0;
  for (int i = lane; i < NS * 4; i += 64)
    keys[nk++] = pb[(size_t)(i >> 2) * (G_N * 4) + (i & 3)];
  u64 top[4] = {0ull, 0ull, 0ull, 0ull};
  for (int q = 0; q < nk; q++) top4_insert(top, keys[q]);
  wave_merge_top4(top);
  if (lane == 0) {
    u64* dst = top4 + ((size_t)b * G_N + g) * 4;
    #pragma unroll
    for (int k = 0; k < 4; k++) dst[k] = top[k];
  }
  // low-quality matches: every partial entry whose value bits == hq bits.
  // atomicOr's old value dedups hist/npos across all setters (incl. k_main).
  u32 hqb = (u32)(__shfl(top[0], 0) >> 32);
  u32 kk0, kk1; image_key(b, kk0, kk1);
  for (int q = 0; q < nk; q++) {
    u64 key = keys[q];
    u32 aidx = ~(u32)key;
    if ((u32)(key >> 32) == hqb && aidx < A_N) {
      u64 bit = 1ull << (aidx & 63);
      u64 old = atomicOr(&posA[(size_t)b * NWORD + (aidx >> 6)], bit);
      if (!(old & bit)) {
        atomicAdd(&hist[b * 4096 + (rbits_for(kk0, kk1, aidx) >> 20)], 1u);
        atomicAdd(&npos[b], 1u);
      }
    }
  }
}

// ---------------- Kernel 3: local bin selection + collect fine candidates ----------------
// grid (NS, B).
__launch_bounds__(256)
__global__ void k_collect(const u64* __restrict__ posA,
                          const u32* __restrict__ npos, const u32* __restrict__ hist,
                          int2* __restrict__ binsel,
                          u32* __restrict__ fine, u32* __restrict__ fcnt) {
  const int b = blockIdx.y;
  const int t = threadIdx.x;
  __shared__ u32 red[256];
  __shared__ int sbin;

  const u32* hb = hist + b * 4096;
  u32 local = 0;
  for (int j = 0; j < 16; j++) local += hb[t * 16 + j];
  red[t] = local;
  __syncthreads();
  if (t == 0) {
    if (npos[b] <= MAX_POS) {
      sbin = -1;
      binsel[b] = make_int2(-1, 0);          // duplicate identical writes across blocks
    } else {
      u32 cum = 0; int chunk = 0;
      for (int i = 0; i < 256; i++) {
        if (cum + red[i] >= MAX_POS) { chunk = i; break; }
        cum += red[i];
      }
      int tb = chunk * 16; u32 before = cum;
      for (int j = 0; j < 16; j++) {
        u32 h = hb[chunk * 16 + j];
        if (before + h >= MAX_POS) { tb = chunk * 16 + j; break; }
        before += h;
      }
      sbin = tb;
      binsel[b] = make_int2(tb, (int)before);
    }
  }
  __syncthreads();
  const int stb = sbin;
  if (stb < 0) return;

  u32 k0, k1; image_key(b, k0, k1);
  const int a0 = blockIdx.x * AS;
  const u64* pa = posA + (size_t)b * NWORD;
  for (int j = t; j < AS; j += 256) {
    int a = a0 + j;
    if (a >= A_N) break;
    if (!((pa[a >> 6] >> (a & 63)) & 1ull)) continue;
    u32 rb = rbits_for(k0, k1, (u32)a);
    if ((int)(rb >> 20) != stb) continue;
    u32 idx = atomicAdd(&fcnt[b], 1u);
    if (idx < FINE_CAP) fine[b * FINE_CAP + idx] = (((rb >> 9) & 0x7FFu) << 18) | (u32)a;
  }
}

// ---------------- Kernel 4: local Tstar + per-gt counts of selected ----------------
// grid (NS, B).
__launch_bounds__(256)
__global__ void k_count(const float4* __restrict__ anchors, const float4* __restrict__ gt,
                        const u64* __restrict__ posA,
                        const int2* __restrict__ binsel, const u32* __restrict__ fine,
                        const u32* __restrict__ fcnt, u32* __restrict__ cnt) {
  const int b = blockIdx.y;
  const int t = threadIdx.x;
  __shared__ float sg[5][64];
  __shared__ u64 sT;

  if (t < 64) {
    float x0, y0, x1, y1, ar;
    conv_box(gt[(size_t)b * G_N + t], x0, y0, x1, y1, ar);
    sg[0][t] = x0; sg[1][t] = y0; sg[2][t] = x1; sg[3][t] = y1; sg[4][t] = ar;
    // wave 0: compute Tstar locally (binary search over the small fine list)
    int2 bs = binsel[b];
    u64 T = ~0ull;
    if (bs.x >= 0) {
      const int m = min((int)fcnt[b], FINE_CAP);
      const u32 need = (u32)(MAX_POS - bs.y);   // >= 1
      const u32* fb = fine + b * FINE_CAP;
      u32 lo = 0, hi = (1u << 29) - 1;
      while (lo < hi) {
        u32 mid = lo + ((hi - lo) >> 1);
        u32 c = 0;
        for (int j = t; j < m; j += 64) c += (fb[j] <= mid) ? 1u : 0u;
        #pragma unroll
        for (int off = 32; off >= 1; off >>= 1) c += __shfl_xor(c, off);
        if (c >= need) hi = mid; else lo = mid + 1;   // uniform across wave
      }
      T = ((u64)(u32)bs.x << 29) | (u64)lo;   // 41-bit threshold
    }
    if (t == 0) sT = T;
  }
  __syncthreads();

  u32 k0, k1; image_key(b, k0, k1);
  const u64 T = sT;
  const int a0 = blockIdx.x * AS;
  const u64* pa = posA + (size_t)b * NWORD;
  const float4* ab = anchors + (size_t)b * A_N;
  for (int j = t; j < AS; j += 256) {
    int a = a0 + j;
    if (a >= A_N) break;
    if (!((pa[a >> 6] >> (a & 63)) & 1ull)) continue;
    if (T != ~0ull) {
      u32 rb = rbits_for(k0, k1, (u32)a);
      if (((((u64)(rb >> 9)) << 18) | (u64)(u32)a) > T) continue;
    }
    float ax0, ay0, ax1, ay1, aar;
    conv_box(ab[a], ax0, ay0, ax1, ay1, aar);
    float bv = -1.0f; int g0 = 0;
    for (int g = 0; g < 64; g++) {
      float v = iou_pair(ax0, ay0, ax1, ay1, aar,
                         sg[0][g], sg[1][g], sg[2][g], sg[3][g], sg[4][g]);
      if (v > bv) { bv = v; g0 = g; }   // strict > = first max (jnp.argmax)
    }
    atomicAdd(&cnt[b * G_N + g0], 1u);
  }
}

// ---------------- Kernel 5: output ----------------
__launch_bounds__(64)
__global__ void k_out(const u64* __restrict__ top4, const u32* __restrict__ cnt,
                      float* __restrict__ out, int sec) {
  const int b = blockIdx.x;
  const int g = threadIdx.x;   // 64 threads
  const u32 c = min(cnt[b * G_N + g], (u32)K_TOP);
  const u64* t4 = top4 + ((size_t)b * G_N + g) * 4;
  #pragma unroll
  for (int k = 0; k < 4; k++) {
    u64 key = t4[k];
    u32 fb = (u32)(key >> 32);
    u32 aidx = ~(u32)key;
    bool valid = (u32)k < c;
    int o = b * (G_N * K_TOP) + g * K_TOP + k;
    out[0 * sec + o] = valid ? (float)aidx : -1.0f;          // pr_inds
    out[1 * sec + o] = valid ? (float)g : -1.0f;             // gt_inds
    out[2 * sec + o] = valid ? 1.0f : 0.0f;                  // valid mask
    out[3 * sec + o] = valid ? __uint_as_float(fb) : 0.0f;   // topk ious
  }
}

extern "C" void kernel_launch(void* const* d_in, const int* in_sizes, int n_in,
                              void* d_out, int out_size, void* d_ws, size_t ws_size,
                              hipStream_t stream) {
  const float4* anchors = (const float4*)d_in[0];  // [B, A, 4] cxcywh
  const float4* gt      = (const float4*)d_in[1];  // [B, G, 4] cxcywh
  float* out = (float*)d_out;                      // 4 x [B, G*K] concatenated

  // Layout — 1,955,904 B, UNDER the R5..R12-proven 2,025,536 B extent:
  //   top4    @ 0          (16,384)
  //     alias: thr_part @ 0 (8*8*64*4 = 16,384) [written k_thresh, read k_main,
  //            dead once k_top4_merge overwrites top4]
  //   partial @ 16,384     (1,605,632) — dead after k_top4_merge;
  //     aliases (written only in dispatches >= 3):
  //       fine   @ 16,384    (131,072)  [k_collect]
  //       binsel @ 147,456   (64)       [k_collect]
  //   posA    @ 1,622,016  (200,704)  [single bitmap; fully ballot-stored]
  //   hist    @ 1,822,720  (131,072)  [zeroed by k_thresh; live from k_main]
  //   small   @ 1,953,792  (2,112): npos(32) fcnt(32) cnt(2,048)
  //            [zeroed by k_thresh s==0 blocks]
  char* ws = (char*)d_ws;
  u64*  top4    = (u64*)(ws);
  u32*  thr_prt = (u32*)(ws);
  u64*  partial = (u64*)(ws + 16384);
  u32*  fine    = (u32*)(ws + 16384);
  int2* binsel  = (int2*)(ws + 147456);
  u64*  posA    = (u64*)(ws + 1622016);
  u32*  hist    = (u32*)(ws + 1822720);
  u32*  npos    = (u32*)(ws + 1953792);
  u32*  fcnt    = (u32*)(ws + 1953824);
  u32*  cnt     = (u32*)(ws + 1953856);

  int sec = out_size / 4;  // 2048 = B*G*K

  k_thresh    <<<dim3(SUB_NS, B_IMG), 512, 0, stream>>>(anchors, gt, thr_prt, hist, npos, fcnt, cnt);
  k_main      <<<dim3(NS, B_IMG), 512, 0, stream>>>(anchors, gt, thr_prt, partial, posA, hist, npos);
  k_top4_merge<<<dim3(G_N, B_IMG), 64, 0, stream>>>(partial, top4, posA, hist, npos);
  k_collect   <<<dim3(NS, B_IMG), 256, 0, stream>>>(posA, npos, hist, binsel, fine, fcnt);
  k_count     <<<dim3(NS, B_IMG), 256, 0, stream>>>(anchors, gt, posA, binsel, fine, fcnt, cnt);
  k_out       <<<dim3(B_IMG), 64, 0, stream>>>(top4, cnt, out, sec);
}

// Round 7
// 269.893 us; speedup vs baseline: 1.0579x; 1.0027x over previous
//
#include <hip/hip_runtime.h>
#include <stdint.h>

// Stage1Assigner (RPN matcher + subsample + top-k per GT) for MI355X.
// B=8 images, A=200000 anchors, G=64 GTs, K=4, thresholds 0.3/0.7, 128 max pos.
//
// PRNG: JAX threefry, jax_threefry_partitionable=True:
//   keys[b] = threefry2x32((0,42),(0,b));  bits[a] = y0^y1 of threefry2x32(key_b,(0,a))
// Selection of 128 positives = 128 lexicographically smallest (bits>>9, a).
//
// R14 vs R13 (counter-driven): essential arithmetic is ~15 VALU/pair -> ~20us
// chip-wide, but k_main measured 130us @ VALUBusy 67% -> the compiled loop
// issues ~4x the essential insts (4 ballot-gated survivor blocks per iter:
// v_cmp+s_or+s_cbranch+exec churn even when skipped, u64 insert state live,
// bit/ni bookkeeping). R14 splits the gg-group loop into:
//   pass A (hot): per j-step compute 4 screens only, OR into a per-lane u32
//     candidate mask (cand |= bit). No ballots, no branches, no u64 state.
//   pass B (cold): per set bit (ffs walk, ~0.3 bits/lane) recompute the 4
//     IoUs from the still-resident LDS tile; exact div, >=0.7 bit, per-lane
//     top-4 insert (T/h were always per-lane; ballots were only a skip
//     heuristic). Ascending-bit walk = ascending-j = identical per-lane
//     insert order -> bit-identical output. Screens recompute bit-identical
//     booleans from identical LDS inputs (IEEE, contract off).
// Also reverts R13's combined-ballot gate (measured -8%: it was the
// regression). Keeps R13's dispatch absorption (zero->k_thresh,
// hist->k_main/k_top4_merge, single pos bitmap). 6 dispatches.
//
// Screen (R11, proven): thrG[gt] = max over 8 sampled slices of the
// 4th-of-lane-maxima of approx q = inter*rcp(uni); sample-4th <= global-4th.
//   t~ = bits(min(thrG - 16ulp, 0.7f - 8ulp)) - 8ulp  (rcp err <= ~2.5 ulp
//   << 16-ulp slack; 8-ulp product margin covers binade edges; denormal
//   flush -> never-skip; thrG=0 -> screen passes everything -> safe).
// Value-0 fake entries (lanes with no candidates keep T=0) are displaced
// whenever a gt has >=4 anchors with iou>0 globally (guaranteed here).
//
// IoU is fp-contract(off) IEEE per-op: identical bits across all passes and
// matches XLA per-HLO rounding.

#pragma clang fp contract(off)

#define B_IMG 8
#define A_N 200000
#define G_N 64
#define K_TOP 4
#define MAX_POS 128
#define FINE_CAP 4096
#define AS 2048
#define NS 98            // ceil(200000/2048)
#define SUB_NS 8         // sampled slices for the threshold pass
#define WPS 32           // u64 ballot words per slice
#define NWORD 3136       // NS*WPS words of pos bits per image

typedef unsigned long long u64;
typedef unsigned int u32;

__device__ __forceinline__ u32 rotl32(u32 v, int n) { return (v << n) | (v >> (32 - n)); }

__device__ __forceinline__ void tf_round(u32& x0, u32& x1, int r) {
  x0 += x1; x1 = rotl32(x1, r); x1 ^= x0;
}

__device__ __forceinline__ void threefry2x32(u32 k0, u32 k1, u32& x0, u32& x1) {
  u32 ks2 = 0x1BD11BDAu ^ k0 ^ k1;
  x0 += k0; x1 += k1;
  tf_round(x0,x1,13); tf_round(x0,x1,15); tf_round(x0,x1,26); tf_round(x0,x1,6);
  x0 += k1; x1 += ks2 + 1u;
  tf_round(x0,x1,17); tf_round(x0,x1,29); tf_round(x0,x1,16); tf_round(x0,x1,24);
  x0 += ks2; x1 += k0 + 2u;
  tf_round(x0,x1,13); tf_round(x0,x1,15); tf_round(x0,x1,26); tf_round(x0,x1,6);
  x0 += k0; x1 += k1 + 3u;
  tf_round(x0,x1,17); tf_round(x0,x1,29); tf_round(x0,x1,16); tf_round(x0,x1,24);
  x0 += k1; x1 += ks2 + 4u;
  tf_round(x0,x1,13); tf_round(x0,x1,15); tf_round(x0,x1,26); tf_round(x0,x1,6);
  x0 += ks2; x1 += k0 + 5u;
}

__device__ __forceinline__ void image_key(int b, u32& kb0, u32& kb1) {
  u32 x0 = 0u, x1 = (u32)b;
  threefry2x32(0u, 42u, x0, x1);
  kb0 = x0; kb1 = x1;
}

__device__ __forceinline__ u32 rbits_for(u32 k0, u32 k1, u32 a) {
  u32 x0 = 0u, x1 = a;
  threefry2x32(k0, k1, x0, x1);
  return x0 ^ x1;
}

__device__ __forceinline__ void conv_box(float4 bx, float& x0, float& y0,
                                         float& x1, float& y1, float& area) {
  #pragma clang fp contract(off)
  x0 = bx.x - 0.5f * bx.z;
  y0 = bx.y - 0.5f * bx.w;
  x1 = bx.x + 0.5f * bx.z;
  y1 = bx.y + 0.5f * bx.w;
  area = (x1 - x0) * (y1 - y0);
}

__device__ __forceinline__ float iou_pair(float ax0, float ay0, float ax1, float ay1, float aarea,
                                          float gx0, float gy0, float gx1, float gy1, float garea) {
  #pragma clang fp contract(off)
  float ltx = fmaxf(gx0, ax0), lty = fmaxf(gy0, ay0);
  float rbx = fminf(gx1, ax1), rby = fminf(gy1, ay1);
  float w = fmaxf(rbx - ltx, 0.0f), h = fmaxf(rby - lty, 0.0f);
  float inter = w * h;
  float uni = (garea + aarea) - inter;
  return inter / uni;
}

// inter/uni only (no division) — same rounding sequence as iou_pair's prefix.
__device__ __forceinline__ void iou_parts(float ax0, float ay0, float ax1, float ay1, float aarea,
                                          float gx0, float gy0, float gx1, float gy1, float garea,
                                          float& inter, float& uni) {
  #pragma clang fp contract(off)
  float ltx = fmaxf(gx0, ax0), lty = fmaxf(gy0, ay0);
  float rbx = fminf(gx1, ax1), rby = fminf(gy1, ay1);
  float w = fmaxf(rbx - ltx, 0.0f), h = fmaxf(rby - lty, 0.0f);
  inter = w * h;
  uni = (garea + aarea) - inter;
}

__device__ __forceinline__ void top4_insert(u64 (&top)[4], u64 key) {
  if (key > top[3]) {
    if (key > top[0])      { top[3]=top[2]; top[2]=top[1]; top[1]=top[0]; top[0]=key; }
    else if (key > top[1]) { top[3]=top[2]; top[2]=top[1]; top[1]=key; }
    else if (key > top[2]) { top[3]=top[2]; top[2]=key; }
    else                   { top[3]=key; }
  }
}

__device__ __forceinline__ void wave_merge_top4(u64 (&top)[4]) {
  for (int off = 32; off >= 1; off >>= 1) {
    u64 o[4];
    #pragma unroll
    for (int k = 0; k < 4; k++) o[k] = __shfl_down(top[k], (unsigned)off);
    u64 m[4]; int i = 0, j = 0;
    #pragma unroll
    for (int k = 0; k < 4; k++) m[k] = (top[i] >= o[j]) ? top[i++] : o[j++];
    #pragma unroll
    for (int k = 0; k < 4; k++) top[k] = m[k];
  }
}

__device__ __forceinline__ void wave_merge_top4_u32(u32 (&top)[4]) {
  for (int off = 32; off >= 1; off >>= 1) {
    u32 o[4];
    #pragma unroll
    for (int k = 0; k < 4; k++) o[k] = __shfl_down(top[k], (unsigned)off);
    u32 m[4]; int i = 0, j = 0;
    #pragma unroll
    for (int k = 0; k < 4; k++) m[k] = (top[i] >= o[j]) ? top[i++] : o[j++];
    #pragma unroll
    for (int k = 0; k < 4; k++) top[k] = m[k];
  }
}

// conservative screen threshold: t~ = bitcast(max(tau,8)-8)  (tau = f32 bits)
__device__ __forceinline__ float screen_thresh(u32 tau) {
  u32 tb = (tau > 8u) ? (tau - 8u) : 0u;
  return __uint_as_float(tb);
}

// ---------------- Kernel 0: sampled threshold pass (+ zero hist & small state) ----------------
// grid (SUB_NS, B); block 512 = 8 waves; wave w handles gt-groups {2w, 2w+1}.
// Per (slice,gt): Q4 = 4th-largest of the 64 lane maxima of approx q. Raw Q4
// written to thr_part[b][s][gt]; k_main reduces with max over s.
// 64 blocks x 512 threads = 32768 = exactly one hist word each (zeroing).
__launch_bounds__(512, 4)
__global__ void k_thresh(const float4* __restrict__ anchors, const float4* __restrict__ gt,
                         u32* __restrict__ thr_part, u32* __restrict__ hist,
                         u32* __restrict__ npos, u32* __restrict__ fcnt,
                         u32* __restrict__ cnt) {
  const int s = blockIdx.x;        // 0..SUB_NS-1, all full slices
  const int b = blockIdx.y;
  const int t = threadIdx.x;
  const int wave = t >> 6, lane = t & 63;

  __shared__ float4 sxy[AS];
  __shared__ float  sg[5][64];

  // zero hist: one word per thread across the whole grid
  hist[(b * SUB_NS + s) * 512 + t] = 0;
  if (s == 0) {
    if (t < 64) cnt[b * G_N + t] = 0;
    if (t == 0) { fcnt[b] = 0; npos[b] = 0; }
  }

  const int base = s * AS;
  const float4* ab = anchors + (size_t)b * A_N + base;

  for (int j = t; j < AS; j += 512) {
    float x0, y0, x1, y1, ar;
    conv_box(ab[j], x0, y0, x1, y1, ar);
    sxy[j] = make_float4(x0, y0, x1, y1);
  }
  if (t < 64) {
    float x0, y0, x1, y1, ar;
    conv_box(gt[(size_t)b * G_N + t], x0, y0, x1, y1, ar);
    sg[0][t] = x0; sg[1][t] = y0; sg[2][t] = x1; sg[3][t] = y1; sg[4][t] = ar;
  }
  __syncthreads();

  for (int gg = 0; gg < 2; gg++) {
    const int gi = (wave * 2 + gg) * 4;
    const float g0x0 = sg[0][gi],   g0y0 = sg[1][gi],   g0x1 = sg[2][gi],   g0y1 = sg[3][gi],   g0a = sg[4][gi];
    const float g1x0 = sg[0][gi+1], g1y0 = sg[1][gi+1], g1x1 = sg[2][gi+1], g1y1 = sg[3][gi+1], g1a = sg[4][gi+1];
    const float g2x0 = sg[0][gi+2], g2y0 = sg[1][gi+2], g2x1 = sg[2][gi+2], g2y1 = sg[3][gi+2], g2a = sg[4][gi+2];
    const float g3x0 = sg[0][gi+3], g3y0 = sg[1][gi+3], g3x1 = sg[2][gi+3], g3y1 = sg[3][gi+3], g3a = sg[4][gi+3];

    u32 q0 = 0, q1 = 0, q2 = 0, q3 = 0;
    for (int j = lane; j < AS; j += 64) {
      float4 x = sxy[j];
      float aarea = (x.z - x.x) * (x.w - x.y);
      float i0, u0, i1, u1, i2, u2, i3, u3;
      iou_parts(x.x, x.y, x.z, x.w, aarea, g0x0, g0y0, g0x1, g0y1, g0a, i0, u0);
      iou_parts(x.x, x.y, x.z, x.w, aarea, g1x0, g1y0, g1x1, g1y1, g1a, i1, u1);
      iou_parts(x.x, x.y, x.z, x.w, aarea, g2x0, g2y0, g2x1, g2y1, g2a, i2, u2);
      iou_parts(x.x, x.y, x.z, x.w, aarea, g3x0, g3y0, g3x1, g3y1, g3a, i3, u3);
      q0 = max(q0, __float_as_uint(i0 * __builtin_amdgcn_rcpf(u0)));
      q1 = max(q1, __float_as_uint(i1 * __builtin_amdgcn_rcpf(u1)));
      q2 = max(q2, __float_as_uint(i2 * __builtin_amdgcn_rcpf(u2)));
      q3 = max(q3, __float_as_uint(i3 * __builtin_amdgcn_rcpf(u3)));
    }
    u32 Q0[4] = {q0,0,0,0}, Q1[4] = {q1,0,0,0}, Q2[4] = {q2,0,0,0}, Q3[4] = {q3,0,0,0};
    wave_merge_top4_u32(Q0);
    wave_merge_top4_u32(Q1);
    wave_merge_top4_u32(Q2);
    wave_merge_top4_u32(Q3);
    if (lane == 0) {
      u32* dst = thr_part + ((size_t)b * SUB_NS + s) * G_N + gi;
      dst[0] = Q0[3]; dst[1] = Q1[3]; dst[2] = Q2[3]; dst[3] = Q3[3];
    }
  }
}

// ---------------- Kernel 1: screened exact pass + pos bitmap + hist ----------------
// grid (NS, B); block 512 = 8 waves; wave w handles gt-groups {2w, 2w+1}.
// Per gg-group: pass A (hot, branchless) builds a per-lane candidate bitmask;
// pass B (cold) ffs-walks it and runs the exact survivor logic per-lane.
// Ballot phase ORs ALL 8 wave masks -> ONE pos bitmap; wave 0 pops its bits,
// threefry-hists them and bumps npos.
// launch_bounds (512,4): VGPR cap 128 — no spill (R8's (512,8) spilled).
__launch_bounds__(512, 4)
__global__ void k_main(const float4* __restrict__ anchors, const float4* __restrict__ gt,
                       const u32* __restrict__ thr_part,
                       u64* __restrict__ partial, u64* __restrict__ posA,
                       u32* __restrict__ hist, u32* __restrict__ npos) {
  const int s = blockIdx.x;
  const int b = blockIdx.y;
  const int t = threadIdx.x;
  const int wave = t >> 6, lane = t & 63;

  __shared__ float4 sxy[AS];        // converted xyxy; reused as wm after gp loop
  __shared__ float  sg[5][64];
  __shared__ float  sthr[64];       // per-gt screen thresholds (slack applied)
  u32* wm = (u32*)sxy;

  const int base = s * AS;
  const int acnt = min(AS, A_N - base);
  const float4* ab = anchors + (size_t)b * A_N + base;

  for (int j = t; j < acnt; j += 512) {
    float x0, y0, x1, y1, ar;
    conv_box(ab[j], x0, y0, x1, y1, ar);
    sxy[j] = make_float4(x0, y0, x1, y1);
  }
  if (t < 64) {
    float x0, y0, x1, y1, ar;
    conv_box(gt[(size_t)b * G_N + t], x0, y0, x1, y1, ar);
    sg[0][t] = x0; sg[1][t] = y0; sg[2][t] = x1; sg[3][t] = y1; sg[4][t] = ar;
    // global sampled threshold for gt t: max over the SUB_NS slice Q4s,
    // then the standard 16-ulp rcp slack + (0.7f - 8ulp) cap + 8-ulp margin.
    u32 mx = 0;
    for (int ss = 0; ss < SUB_NS; ss++)
      mx = max(mx, thr_part[((size_t)b * SUB_NS + ss) * G_N + t]);
    const u32 L7 = 0x3F333333u - 8u;   // 0.7f bits - 8 ulp
    sthr[t] = screen_thresh(min(mx > 16u ? mx - 16u : 0u, L7));
  }
  __syncthreads();

  u32 m = 0;   // bit k: anchor base+64k+lane has iou>=0.7 vs any of this wave's gts
  for (int gg = 0; gg < 2; gg++) {
    const int gp = wave * 2 + gg;      // 0..15
    const int gi = gp * 4;             // global gt index of group start
    const float g0x0 = sg[0][gi],   g0y0 = sg[1][gi],   g0x1 = sg[2][gi],   g0y1 = sg[3][gi],   g0a = sg[4][gi];
    const float g1x0 = sg[0][gi+1], g1y0 = sg[1][gi+1], g1x1 = sg[2][gi+1], g1y1 = sg[3][gi+1], g1a = sg[4][gi+1];
    const float g2x0 = sg[0][gi+2], g2y0 = sg[1][gi+2], g2x1 = sg[2][gi+2], g2y1 = sg[3][gi+2], g2a = sg[4][gi+2];
    const float g3x0 = sg[0][gi+3], g3y0 = sg[1][gi+3], g3x1 = sg[2][gi+3], g3y1 = sg[3][gi+3], g3a = sg[4][gi+3];
    const float t0 = sthr[gi], t1 = sthr[gi+1], t2 = sthr[gi+2], t3 = sthr[gi+3];

    // ---- pass A (hot): branchless candidate mask, no survivor state ----
    u32 cand = 0;
    {
      u32 bit = 1u;
      for (int j = lane; j < acnt; j += 64, bit <<= 1) {
        float4 x = sxy[j];
        float aarea = (x.z - x.x) * (x.w - x.y);
        float i0, u0, i1, u1, i2, u2, i3, u3;
        iou_parts(x.x, x.y, x.z, x.w, aarea, g0x0, g0y0, g0x1, g0y1, g0a, i0, u0);
        iou_parts(x.x, x.y, x.z, x.w, aarea, g1x0, g1y0, g1x1, g1y1, g1a, i1, u1);
        iou_parts(x.x, x.y, x.z, x.w, aarea, g2x0, g2y0, g2x1, g2y1, g2a, i2, u2);
        iou_parts(x.x, x.y, x.z, x.w, aarea, g3x0, g3y0, g3x1, g3y1, g3a, i3, u3);
        bool any = (i0 >= t0 * u0) | (i1 >= t1 * u1) | (i2 >= t2 * u2) | (i3 >= t3 * u3);
        cand |= any ? bit : 0u;
      }
    }

    // ---- pass B (cold): exact survivor logic per candidate, per-lane ----
    // Ascending-bit walk = ascending-j per lane = identical insert order to
    // the R11 formulation (T/h are per-lane state; ballots there were only a
    // wave-level skip heuristic). Screens recompute identical booleans.
    u64 T0[4] = {0,0,0,0}, T1[4] = {0,0,0,0}, T2[4] = {0,0,0,0}, T3[4] = {0,0,0,0};
    u32 h0 = 0, h1 = 0, h2 = 0, h3 = 0;
    u32 cc = cand;
    while (__ballot(cc != 0u)) {
      if (cc) {
        int jj = __ffs((int)cc) - 1; cc &= cc - 1;
        int j = (jj << 6) + lane;
        u32 bitj = 1u << jj;
        float4 x = sxy[j];
        float aarea = (x.z - x.x) * (x.w - x.y);
        float i0, u0, i1, u1, i2, u2, i3, u3;
        iou_parts(x.x, x.y, x.z, x.w, aarea, g0x0, g0y0, g0x1, g0y1, g0a, i0, u0);
        iou_parts(x.x, x.y, x.z, x.w, aarea, g1x0, g1y0, g1x1, g1y1, g1a, i1, u1);
        iou_parts(x.x, x.y, x.z, x.w, aarea, g2x0, g2y0, g2x1, g2y1, g2a, i2, u2);
        iou_parts(x.x, x.y, x.z, x.w, aarea, g3x0, g3y0, g3x1, g3y1, g3a, i3, u3);
        u32 ni = ~(u32)(base + j);
        if (i0 >= t0 * u0) {
          float v = i0 / u0; if (v >= 0.7f) m |= bitj;
          u32 vb = __float_as_uint(v);
          if (vb >= h0) { top4_insert(T0, ((u64)vb << 32) | (u64)ni); h0 = (u32)(T0[3] >> 32); }
        }
        if (i1 >= t1 * u1) {
          float v = i1 / u1; if (v >= 0.7f) m |= bitj;
          u32 vb = __float_as_uint(v);
          if (vb >= h1) { top4_insert(T1, ((u64)vb << 32) | (u64)ni); h1 = (u32)(T1[3] >> 32); }
        }
        if (i2 >= t2 * u2) {
          float v = i2 / u2; if (v >= 0.7f) m |= bitj;
          u32 vb = __float_as_uint(v);
          if (vb >= h2) { top4_insert(T2, ((u64)vb << 32) | (u64)ni); h2 = (u32)(T2[3] >> 32); }
        }
        if (i3 >= t3 * u3) {
          float v = i3 / u3; if (v >= 0.7f) m |= bitj;
          u32 vb = __float_as_uint(v);
          if (vb >= h3) { top4_insert(T3, ((u64)vb << 32) | (u64)ni); h3 = (u32)(T3[3] >> 32); }
        }
      }
    }
    wave_merge_top4(T0);
    wave_merge_top4(T1);
    wave_merge_top4(T2);
    wave_merge_top4(T3);
    if (lane == 0) {
      u64* dst = partial + (((size_t)b * NS + s) * G_N + gi) * 4;
      #pragma unroll
      for (int k = 0; k < 4; k++) {
        dst[k] = T0[k]; dst[4 + k] = T1[k]; dst[8 + k] = T2[k]; dst[12 + k] = T3[k];
      }
    }
  }

  __syncthreads();      // all waves done reading sxy (wm aliases it)
  wm[t] = m;
  __syncthreads();
  // wave 0: full OR over all 8 wave masks -> one pos bitmap; pop bits for
  // hist + npos (dedup across gts inherent in the OR).
  if (wave == 0) {
    u32 mc = 0;
    #pragma unroll
    for (int w = 0; w < 8; w++) mc |= wm[w * 64 + lane];
    u64* posH = posA + (size_t)b * NWORD + s * WPS;
    for (int k = 0; k < WPS; k++) {
      u64 bal = __ballot((mc >> k) & 1u);
      if (lane == 0) posH[k] = bal;    // plain store — every word covered exactly once
    }
    // hist + npos for this slice's pos anchors
    u32 k0, k1; image_key(b, k0, k1);
    u32 c = (u32)__popc(mc);
    u32 mm = mc;
    while (mm) {
      int k = __ffs((int)mm) - 1; mm &= mm - 1;
      u32 a = (u32)(base + k * 64 + lane);
      atomicAdd(&hist[b * 4096 + (rbits_for(k0, k1, a) >> 20)], 1u);
    }
    #pragma unroll
    for (int off = 32; off >= 1; off >>= 1) c += __shfl_xor(c, off);
    if (lane == 0 && c) atomicAdd(&npos[b], c);
  }
}

// ---------------- Kernel 2: merge partials -> top4; lq anchors -> posA (+hist) ----------------
__launch_bounds__(64)
__global__ void k_top4_merge(const u64* __restrict__ partial, u64* __restrict__ top4,
                             u64* __restrict__ posA,
                             u32* __restrict__ hist, u32* __restrict__ npos) {
  const int b = blockIdx.y, g = blockIdx.x, lane = threadIdx.x;
  const u64* pb = partial + ((size_t)b * NS * G_N + g) * 4;
  u64 keys[7];                       // NS*4 = 392 -> <= 7 per lane
  int nk = 0;
  for (int i = lane; i < NS * 4; i += 64)
    keys[nk++] = pb[(size_t)(i >> 2) * (G_N * 4) + (i & 3)];
  u64 top[4] = {0ull, 0ull, 0ull, 0ull};
  for (int q = 0; q < nk; q++) top4_insert(top, keys[q]);
  wave_merge_top4(top);
  if (lane == 0) {
    u64* dst = top4 + ((size_t)b * G_N + g) * 4;
    #pragma unroll
    for (int k = 0; k < 4; k++) dst[k] = top[k];
  }
  // low-quality matches: every partial entry whose value bits == hq bits.
  // atomicOr's old value dedups hist/npos across all setters (incl. k_main).
  u32 hqb = (u32)(__shfl(top[0], 0) >> 32);
  u32 kk0, kk1; image_key(b, kk0, kk1);
  for (int q = 0; q < nk; q++) {
    u64 key = keys[q];
    u32 aidx = ~(u32)key;
    if ((u32)(key >> 32) == hqb && aidx < A_N) {
      u64 bit = 1ull << (aidx & 63);
      u64 old = atomicOr(&posA[(size_t)b * NWORD + (aidx >> 6)], bit);
      if (!(old & bit)) {
        atomicAdd(&hist[b * 4096 + (rbits_for(kk0, kk1, aidx) >> 20)], 1u);
        atomicAdd(&npos[b], 1u);
      }
    }
  }
}

// ---------------- Kernel 3: local bin selection + collect fine candidates ----------------
// grid (NS, B).
__launch_bounds__(256)
__global__ void k_collect(const u64* __restrict__ posA,
                          const u32* __restrict__ npos, const u32* __restrict__ hist,
                          int2* __restrict__ binsel,
                          u32* __restrict__ fine, u32* __restrict__ fcnt) {
  const int b = blockIdx.y;
  const int t = threadIdx.x;
  __shared__ u32 red[256];
  __shared__ int sbin;

  const u32* hb = hist + b * 4096;
  u32 local = 0;
  for (int j = 0; j < 16; j++) local += hb[t * 16 + j];
  red[t] = local;
  __syncthreads();
  if (t == 0) {
    if (npos[b] <= MAX_POS) {
      sbin = -1;
      binsel[b] = make_int2(-1, 0);          // duplicate identical writes across blocks
    } else {
      u32 cum = 0; int chunk = 0;
      for (int i = 0; i < 256; i++) {
        if (cum + red[i] >= MAX_POS) { chunk = i; break; }
        cum += red[i];
      }
      int tb = chunk * 16; u32 before = cum;
      for (int j = 0; j < 16; j++) {
        u32 h = hb[chunk * 16 + j];
        if (before + h >= MAX_POS) { tb = chunk * 16 + j; break; }
        before += h;
      }
      sbin = tb;
      binsel[b] = make_int2(tb, (int)before);
    }
  }
  __syncthreads();
  const int stb = sbin;
  if (stb < 0) return;

  u32 k0, k1; image_key(b, k0, k1);
  const int a0 = blockIdx.x * AS;
  const u64* pa = posA + (size_t)b * NWORD;
  for (int j = t; j < AS; j += 256) {
    int a = a0 + j;
    if (a >= A_N) break;
    if (!((pa[a >> 6] >> (a & 63)) & 1ull)) continue;
    u32 rb = rbits_for(k0, k1, (u32)a);
    if ((int)(rb >> 20) != stb) continue;
    u32 idx = atomicAdd(&fcnt[b], 1u);
    if (idx < FINE_CAP) fine[b * FINE_CAP + idx] = (((rb >> 9) & 0x7FFu) << 18) | (u32)a;
  }
}

// ---------------- Kernel 4: local Tstar + per-gt counts of selected ----------------
// grid (NS, B).
__launch_bounds__(256)
__global__ void k_count(const float4* __restrict__ anchors, const float4* __restrict__ gt,
                        const u64* __restrict__ posA,
                        const int2* __restrict__ binsel, const u32* __restrict__ fine,
                        const u32* __restrict__ fcnt, u32* __restrict__ cnt) {
  const int b = blockIdx.y;
  const int t = threadIdx.x;
  __shared__ float sg[5][64];
  __shared__ u64 sT;

  if (t < 64) {
    float x0, y0, x1, y1, ar;
    conv_box(gt[(size_t)b * G_N + t], x0, y0, x1, y1, ar);
    sg[0][t] = x0; sg[1][t] = y0; sg[2][t] = x1; sg[3][t] = y1; sg[4][t] = ar;
    // wave 0: compute Tstar locally (binary search over the small fine list)
    int2 bs = binsel[b];
    u64 T = ~0ull;
    if (bs.x >= 0) {
      const int m = min((int)fcnt[b], FINE_CAP);
      const u32 need = (u32)(MAX_POS - bs.y);   // >= 1
      const u32* fb = fine + b * FINE_CAP;
      u32 lo = 0, hi = (1u << 29) - 1;
      while (lo < hi) {
        u32 mid = lo + ((hi - lo) >> 1);
        u32 c = 0;
        for (int j = t; j < m; j += 64) c += (fb[j] <= mid) ? 1u : 0u;
        #pragma unroll
        for (int off = 32; off >= 1; off >>= 1) c += __shfl_xor(c, off);
        if (c >= need) hi = mid; else lo = mid + 1;   // uniform across wave
      }
      T = ((u64)(u32)bs.x << 29) | (u64)lo;   // 41-bit threshold
    }
    if (t == 0) sT = T;
  }
  __syncthreads();

  u32 k0, k1; image_key(b, k0, k1);
  const u64 T = sT;
  const int a0 = blockIdx.x * AS;
  const u64* pa = posA + (size_t)b * NWORD;
  const float4* ab = anchors + (size_t)b * A_N;
  for (int j = t; j < AS; j += 256) {
    int a = a0 + j;
    if (a >= A_N) break;
    if (!((pa[a >> 6] >> (a & 63)) & 1ull)) continue;
    if (T != ~0ull) {
      u32 rb = rbits_for(k0, k1, (u32)a);
      if (((((u64)(rb >> 9)) << 18) | (u64)(u32)a) > T) continue;
    }
    float ax0, ay0, ax1, ay1, aar;
    conv_box(ab[a], ax0, ay0, ax1, ay1, aar);
    float bv = -1.0f; int g0 = 0;
    for (int g = 0; g < 64; g++) {
      float v = iou_pair(ax0, ay0, ax1, ay1, aar,
                         sg[0][g], sg[1][g], sg[2][g], sg[3][g], sg[4][g]);
      if (v > bv) { bv = v; g0 = g; }   // strict > = first max (jnp.argmax)
    }
    atomicAdd(&cnt[b * G_N + g0], 1u);
  }
}

// ---------------- Kernel 5: output ----------------
__launch_bounds__(64)
__global__ void k_out(const u64* __restrict__ top4, const u32* __restrict__ cnt,
                      float* __restrict__ out, int sec) {
  const int b = blockIdx.x;
  const int g = threadIdx.x;   // 64 threads
  const u32 c = min(cnt[b * G_N + g], (u32)K_TOP);
  const u64* t4 = top4 + ((size_t)b * G_N + g) * 4;
  #pragma unroll
  for (int k = 0; k < 4; k++) {
    u64 key = t4[k];
    u32 fb = (u32)(key >> 32);
    u32 aidx = ~(u32)key;
    bool valid = (u32)k < c;
    int o = b * (G_N * K_TOP) + g * K_TOP + k;
    out[0 * sec + o] = valid ? (float)aidx : -1.0f;          // pr_inds
    out[1 * sec + o] = valid ? (float)g : -1.0f;             // gt_inds
    out[2 * sec + o] = valid ? 1.0f : 0.0f;                  // valid mask
    out[3 * sec + o] = valid ? __uint_as_float(fb) : 0.0f;   // topk ious
  }
}

extern "C" void kernel_launch(void* const* d_in, const int* in_sizes, int n_in,
                              void* d_out, int out_size, void* d_ws, size_t ws_size,
                              hipStream_t stream) {
  const float4* anchors = (const float4*)d_in[0];  // [B, A, 4] cxcywh
  const float4* gt      = (const float4*)d_in[1];  // [B, G, 4] cxcywh
  float* out = (float*)d_out;                      // 4 x [B, G*K] concatenated

  // Layout — 1,955,904 B, UNDER the R5..R13-proven 2,025,536 B extent:
  //   top4    @ 0          (16,384)
  //     alias: thr_part @ 0 (8*8*64*4 = 16,384) [written k_thresh, read k_main,
  //            dead once k_top4_merge overwrites top4]
  //   partial @ 16,384     (1,605,632) — dead after k_top4_merge;
  //     aliases (written only in dispatches >= 3):
  //       fine   @ 16,384    (131,072)  [k_collect]
  //       binsel @ 147,456   (64)       [k_collect]
  //   posA    @ 1,622,016  (200,704)  [single bitmap; fully ballot-stored]
  //   hist    @ 1,822,720  (131,072)  [zeroed by k_thresh; live from k_main]
  //   small   @ 1,953,792  (2,112): npos(32) fcnt(32) cnt(2,048)
  //            [zeroed by k_thresh s==0 blocks]
  char* ws = (char*)d_ws;
  u64*  top4    = (u64*)(ws);
  u32*  thr_prt = (u32*)(ws);
  u64*  partial = (u64*)(ws + 16384);
  u32*  fine    = (u32*)(ws + 16384);
  int2* binsel  = (int2*)(ws + 147456);
  u64*  posA    = (u64*)(ws + 1622016);
  u32*  hist    = (u32*)(ws + 1822720);
  u32*  npos    = (u32*)(ws + 1953792);
  u32*  fcnt    = (u32*)(ws + 1953824);
  u32*  cnt     = (u32*)(ws + 1953856);

  int sec = out_size / 4;  // 2048 = B*G*K

  k_thresh    <<<dim3(SUB_NS, B_IMG), 512, 0, stream>>>(anchors, gt, thr_prt, hist, npos, fcnt, cnt);
  k_main      <<<dim3(NS, B_IMG), 512, 0, stream>>>(anchors, gt, thr_prt, partial, posA, hist, npos);
  k_top4_merge<<<dim3(G_N, B_IMG), 64, 0, stream>>>(partial, top4, posA, hist, npos);
  k_collect   <<<dim3(NS, B_IMG), 256, 0, stream>>>(posA, npos, hist, binsel, fine, fcnt);
  k_count     <<<dim3(NS, B_IMG), 256, 0, stream>>>(anchors, gt, posA, binsel, fine, fcnt, cnt);
  k_out       <<<dim3(B_IMG), 64, 0, stream>>>(top4, cnt, out, sec);
}

// Round 8
// 251.070 us; speedup vs baseline: 1.1372x; 1.0750x over previous
//
#include <hip/hip_runtime.h>
#include <stdint.h>

// Stage1Assigner (RPN matcher + subsample + top-k per GT) for MI355X.
// B=8 images, A=200000 anchors, G=64 GTs, K=4, thresholds 0.3/0.7, 128 max pos.
//
// PRNG: JAX threefry, jax_threefry_partitionable=True:
//   keys[b] = threefry2x32((0,42),(0,b));  bits[a] = y0^y1 of threefry2x32(key_b,(0,a))
// Selection of 128 positives = 128 lexicographically smallest (bits>>9, a).
//
// R15 vs R14 (counter-driven):
//  * R14's pass-A/B split spilled (WRITE_SIZE 4.3->40MB, VGPR pinned at 64).
//    k_main REVERTED to the R11 4-ballot loop (fastest measured, 120.7us,
//    no spill), keeping the R13 epilogue (single pos bitmap + inline hist).
//  * k_thresh's wall time is per-WAVE serial depth (64 j-iters x ~60 VALU =
//    same depth as a full k_main pass ~= 60us hidden cost; it never showed in
//    top-5). R15 spreads the SAME 16384 sampled anchors over 256 blocks:
//    grid (16,B,2), sub-slices of 1024 anchors, ONE gt-group per wave ->
//    16 j-iters/wave -> wall ~5-10us. 4th-of-lane-maxima over a 1024-anchor
//    subset is still a lower bound on the global 4th-largest (4 distinct
//    anchors in 4 distinct lanes) -> conservative screen proof unchanged;
//    thresholds slightly looser, survivors still rare.
//  * thr_part is now 8*16*64*u32 = 32KB -> moved to the free region after
//    'small' (no longer aliases top4); extent 1,988,672 <= proven 2,025,536.
//
// Screen: thrG[gt] = max over 16 sampled sub-slices of Q4; t~ =
//   bits(min(thrG - 16ulp, 0.7f - 8ulp)) - 8ulp  (rcp err <= ~2.5 ulp <<
//   16-ulp slack; 8-ulp product margin covers binade edges; denormal flush ->
//   never-skip; thrG=0 -> screen passes everything -> safe).
// All exact comparisons identical to R5..R14 -> bit-identical output.
// Value-0 fake entries (masked lanes insert vb=0 early) are displaced
// whenever a gt has >=4 anchors with iou>0 globally (guaranteed here).
//
// IoU is fp-contract(off) IEEE per-op: identical bits across all passes and
// matches XLA per-HLO rounding.

#pragma clang fp contract(off)

#define B_IMG 8
#define A_N 200000
#define G_N 64
#define K_TOP 4
#define MAX_POS 128
#define FINE_CAP 4096
#define AS 2048
#define NS 98            // ceil(200000/2048)
#define SUB_SL 16        // sampled sub-slices (1024 anchors each)
#define SUB_AS 1024
#define WPS 32           // u64 ballot words per slice
#define NWORD 3136       // NS*WPS words of pos bits per image

typedef unsigned long long u64;
typedef unsigned int u32;

__device__ __forceinline__ u32 rotl32(u32 v, int n) { return (v << n) | (v >> (32 - n)); }

__device__ __forceinline__ void tf_round(u32& x0, u32& x1, int r) {
  x0 += x1; x1 = rotl32(x1, r); x1 ^= x0;
}

__device__ __forceinline__ void threefry2x32(u32 k0, u32 k1, u32& x0, u32& x1) {
  u32 ks2 = 0x1BD11BDAu ^ k0 ^ k1;
  x0 += k0; x1 += k1;
  tf_round(x0,x1,13); tf_round(x0,x1,15); tf_round(x0,x1,26); tf_round(x0,x1,6);
  x0 += k1; x1 += ks2 + 1u;
  tf_round(x0,x1,17); tf_round(x0,x1,29); tf_round(x0,x1,16); tf_round(x0,x1,24);
  x0 += ks2; x1 += k0 + 2u;
  tf_round(x0,x1,13); tf_round(x0,x1,15); tf_round(x0,x1,26); tf_round(x0,x1,6);
  x0 += k0; x1 += k1 + 3u;
  tf_round(x0,x1,17); tf_round(x0,x1,29); tf_round(x0,x1,16); tf_round(x0,x1,24);
  x0 += k1; x1 += ks2 + 4u;
  tf_round(x0,x1,13); tf_round(x0,x1,15); tf_round(x0,x1,26); tf_round(x0,x1,6);
  x0 += ks2; x1 += k0 + 5u;
}

__device__ __forceinline__ void image_key(int b, u32& kb0, u32& kb1) {
  u32 x0 = 0u, x1 = (u32)b;
  threefry2x32(0u, 42u, x0, x1);
  kb0 = x0; kb1 = x1;
}

__device__ __forceinline__ u32 rbits_for(u32 k0, u32 k1, u32 a) {
  u32 x0 = 0u, x1 = a;
  threefry2x32(k0, k1, x0, x1);
  return x0 ^ x1;
}

__device__ __forceinline__ void conv_box(float4 bx, float& x0, float& y0,
                                         float& x1, float& y1, float& area) {
  #pragma clang fp contract(off)
  x0 = bx.x - 0.5f * bx.z;
  y0 = bx.y - 0.5f * bx.w;
  x1 = bx.x + 0.5f * bx.z;
  y1 = bx.y + 0.5f * bx.w;
  area = (x1 - x0) * (y1 - y0);
}

__device__ __forceinline__ float iou_pair(float ax0, float ay0, float ax1, float ay1, float aarea,
                                          float gx0, float gy0, float gx1, float gy1, float garea) {
  #pragma clang fp contract(off)
  float ltx = fmaxf(gx0, ax0), lty = fmaxf(gy0, ay0);
  float rbx = fminf(gx1, ax1), rby = fminf(gy1, ay1);
  float w = fmaxf(rbx - ltx, 0.0f), h = fmaxf(rby - lty, 0.0f);
  float inter = w * h;
  float uni = (garea + aarea) - inter;
  return inter / uni;
}

// inter/uni only (no division) — same rounding sequence as iou_pair's prefix.
__device__ __forceinline__ void iou_parts(float ax0, float ay0, float ax1, float ay1, float aarea,
                                          float gx0, float gy0, float gx1, float gy1, float garea,
                                          float& inter, float& uni) {
  #pragma clang fp contract(off)
  float ltx = fmaxf(gx0, ax0), lty = fmaxf(gy0, ay0);
  float rbx = fminf(gx1, ax1), rby = fminf(gy1, ay1);
  float w = fmaxf(rbx - ltx, 0.0f), h = fmaxf(rby - lty, 0.0f);
  inter = w * h;
  uni = (garea + aarea) - inter;
}

__device__ __forceinline__ void top4_insert(u64 (&top)[4], u64 key) {
  if (key > top[3]) {
    if (key > top[0])      { top[3]=top[2]; top[2]=top[1]; top[1]=top[0]; top[0]=key; }
    else if (key > top[1]) { top[3]=top[2]; top[2]=top[1]; top[1]=key; }
    else if (key > top[2]) { top[3]=top[2]; top[2]=key; }
    else                   { top[3]=key; }
  }
}

__device__ __forceinline__ void wave_merge_top4(u64 (&top)[4]) {
  for (int off = 32; off >= 1; off >>= 1) {
    u64 o[4];
    #pragma unroll
    for (int k = 0; k < 4; k++) o[k] = __shfl_down(top[k], (unsigned)off);
    u64 m[4]; int i = 0, j = 0;
    #pragma unroll
    for (int k = 0; k < 4; k++) m[k] = (top[i] >= o[j]) ? top[i++] : o[j++];
    #pragma unroll
    for (int k = 0; k < 4; k++) top[k] = m[k];
  }
}

__device__ __forceinline__ void wave_merge_top4_u32(u32 (&top)[4]) {
  for (int off = 32; off >= 1; off >>= 1) {
    u32 o[4];
    #pragma unroll
    for (int k = 0; k < 4; k++) o[k] = __shfl_down(top[k], (unsigned)off);
    u32 m[4]; int i = 0, j = 0;
    #pragma unroll
    for (int k = 0; k < 4; k++) m[k] = (top[i] >= o[j]) ? top[i++] : o[j++];
    #pragma unroll
    for (int k = 0; k < 4; k++) top[k] = m[k];
  }
}

// conservative screen threshold: t~ = bitcast(max(tau,8)-8)  (tau = f32 bits)
__device__ __forceinline__ float screen_thresh(u32 tau) {
  u32 tb = (tau > 8u) ? (tau - 8u) : 0u;
  return __uint_as_float(tb);
}

// ---------------- Kernel 0: sampled threshold pass (+ zero hist & small state) ----------------
// grid (SUB_SL, B, 2); block 512 = 8 waves; wave w handles gt-group
// half*8 + w (ONE group -> 16 j-iters/wave). Sub-slice s = anchors
// [s*1024, s*1024+1024) — total sampled set identical to R11..R14 (0..16383).
// 256 blocks x 512 threads = 131072 threads -> hist (32768 words) zeroed
// by the first 32768 linear threads.
__launch_bounds__(512, 4)
__global__ void k_thresh(const float4* __restrict__ anchors, const float4* __restrict__ gt,
                         u32* __restrict__ thr_part, u32* __restrict__ hist,
                         u32* __restrict__ npos, u32* __restrict__ fcnt,
                         u32* __restrict__ cnt) {
  const int s = blockIdx.x;        // 0..SUB_SL-1
  const int b = blockIdx.y;
  const int half = blockIdx.z;     // gt half
  const int t = threadIdx.x;
  const int wave = t >> 6, lane = t & 63;

  __shared__ float4 sxy[SUB_AS];
  __shared__ float  sg[5][32];

  // zero hist: one word per linear thread for the first 32768 threads
  {
    int lid = ((half * B_IMG + b) * SUB_SL + s) * 512 + t;
    if (lid < B_IMG * 4096) hist[lid] = 0;
  }
  if (s == 0 && half == 0) {
    if (t < 64) cnt[b * G_N + t] = 0;
    if (t == 0) { fcnt[b] = 0; npos[b] = 0; }
  }

  const int base = s * SUB_AS;
  const float4* ab = anchors + (size_t)b * A_N + base;

  for (int j = t; j < SUB_AS; j += 512) {
    float x0, y0, x1, y1, ar;
    conv_box(ab[j], x0, y0, x1, y1, ar);
    sxy[j] = make_float4(x0, y0, x1, y1);
  }
  if (t < 32) {
    float x0, y0, x1, y1, ar;
    conv_box(gt[(size_t)b * G_N + half * 32 + t], x0, y0, x1, y1, ar);
    sg[0][t] = x0; sg[1][t] = y0; sg[2][t] = x1; sg[3][t] = y1; sg[4][t] = ar;
  }
  __syncthreads();

  {
    const int gi = wave * 4;       // local gt index within this half
    const float g0x0 = sg[0][gi],   g0y0 = sg[1][gi],   g0x1 = sg[2][gi],   g0y1 = sg[3][gi],   g0a = sg[4][gi];
    const float g1x0 = sg[0][gi+1], g1y0 = sg[1][gi+1], g1x1 = sg[2][gi+1], g1y1 = sg[3][gi+1], g1a = sg[4][gi+1];
    const float g2x0 = sg[0][gi+2], g2y0 = sg[1][gi+2], g2x1 = sg[2][gi+2], g2y1 = sg[3][gi+2], g2a = sg[4][gi+2];
    const float g3x0 = sg[0][gi+3], g3y0 = sg[1][gi+3], g3x1 = sg[2][gi+3], g3y1 = sg[3][gi+3], g3a = sg[4][gi+3];

    u32 q0 = 0, q1 = 0, q2 = 0, q3 = 0;
    for (int j = lane; j < SUB_AS; j += 64) {
      float4 x = sxy[j];
      float aarea = (x.z - x.x) * (x.w - x.y);
      float i0, u0, i1, u1, i2, u2, i3, u3;
      iou_parts(x.x, x.y, x.z, x.w, aarea, g0x0, g0y0, g0x1, g0y1, g0a, i0, u0);
      iou_parts(x.x, x.y, x.z, x.w, aarea, g1x0, g1y0, g1x1, g1y1, g1a, i1, u1);
      iou_parts(x.x, x.y, x.z, x.w, aarea, g2x0, g2y0, g2x1, g2y1, g2a, i2, u2);
      iou_parts(x.x, x.y, x.z, x.w, aarea, g3x0, g3y0, g3x1, g3y1, g3a, i3, u3);
      q0 = max(q0, __float_as_uint(i0 * __builtin_amdgcn_rcpf(u0)));
      q1 = max(q1, __float_as_uint(i1 * __builtin_amdgcn_rcpf(u1)));
      q2 = max(q2, __float_as_uint(i2 * __builtin_amdgcn_rcpf(u2)));
      q3 = max(q3, __float_as_uint(i3 * __builtin_amdgcn_rcpf(u3)));
    }
    u32 Q0[4] = {q0,0,0,0}, Q1[4] = {q1,0,0,0}, Q2[4] = {q2,0,0,0}, Q3[4] = {q3,0,0,0};
    wave_merge_top4_u32(Q0);
    wave_merge_top4_u32(Q1);
    wave_merge_top4_u32(Q2);
    wave_merge_top4_u32(Q3);
    if (lane == 0) {
      u32* dst = thr_part + ((size_t)b * SUB_SL + s) * G_N + half * 32 + gi;
      dst[0] = Q0[3]; dst[1] = Q1[3]; dst[2] = Q2[3]; dst[3] = Q3[3];
    }
  }
}

// ---------------- Kernel 1: screened exact pass + pos bitmap + hist ----------------
// grid (NS, B); block 512 = 8 waves; wave w handles gt-groups {2w, 2w+1}.
// Inner loop: exact R11 formulation (fastest measured; no spill).
// Epilogue: OR all 8 wave masks -> ONE pos bitmap; wave 0 pops bits for
// hist + npos.
// launch_bounds (512,4): VGPR cap 128 — no spill (R8's (512,8) spilled).
__launch_bounds__(512, 4)
__global__ void k_main(const float4* __restrict__ anchors, const float4* __restrict__ gt,
                       const u32* __restrict__ thr_part,
                       u64* __restrict__ partial, u64* __restrict__ posA,
                       u32* __restrict__ hist, u32* __restrict__ npos) {
  const int s = blockIdx.x;
  const int b = blockIdx.y;
  const int t = threadIdx.x;
  const int wave = t >> 6, lane = t & 63;

  __shared__ float4 sxy[AS];        // converted xyxy; reused as wm after gp loop
  __shared__ float  sg[5][64];
  __shared__ float  sthr[64];       // per-gt screen thresholds (slack applied)
  u32* wm = (u32*)sxy;

  const int base = s * AS;
  const int acnt = min(AS, A_N - base);
  const float4* ab = anchors + (size_t)b * A_N + base;

  for (int j = t; j < acnt; j += 512) {
    float x0, y0, x1, y1, ar;
    conv_box(ab[j], x0, y0, x1, y1, ar);
    sxy[j] = make_float4(x0, y0, x1, y1);
  }
  if (t < 64) {
    float x0, y0, x1, y1, ar;
    conv_box(gt[(size_t)b * G_N + t], x0, y0, x1, y1, ar);
    sg[0][t] = x0; sg[1][t] = y0; sg[2][t] = x1; sg[3][t] = y1; sg[4][t] = ar;
    // global sampled threshold for gt t: max over the SUB_SL sub-slice Q4s,
    // then the standard 16-ulp rcp slack + (0.7f - 8ulp) cap + 8-ulp margin.
    u32 mx = 0;
    for (int ss = 0; ss < SUB_SL; ss++)
      mx = max(mx, thr_part[((size_t)b * SUB_SL + ss) * G_N + t]);
    const u32 L7 = 0x3F333333u - 8u;   // 0.7f bits - 8 ulp
    sthr[t] = screen_thresh(min(mx > 16u ? mx - 16u : 0u, L7));
  }
  __syncthreads();

  u32 m = 0;   // bit k: anchor base+64k+lane has iou>=0.7 vs any of this wave's gts
  for (int gg = 0; gg < 2; gg++) {
    const int gp = wave * 2 + gg;      // 0..15
    const int gi = gp * 4;             // global gt index of group start
    const float g0x0 = sg[0][gi],   g0y0 = sg[1][gi],   g0x1 = sg[2][gi],   g0y1 = sg[3][gi],   g0a = sg[4][gi];
    const float g1x0 = sg[0][gi+1], g1y0 = sg[1][gi+1], g1x1 = sg[2][gi+1], g1y1 = sg[3][gi+1], g1a = sg[4][gi+1];
    const float g2x0 = sg[0][gi+2], g2y0 = sg[1][gi+2], g2x1 = sg[2][gi+2], g2y1 = sg[3][gi+2], g2a = sg[4][gi+2];
    const float g3x0 = sg[0][gi+3], g3y0 = sg[1][gi+3], g3x1 = sg[2][gi+3], g3y1 = sg[3][gi+3], g3a = sg[4][gi+3];
    const float t0 = sthr[gi], t1 = sthr[gi+1], t2 = sthr[gi+2], t3 = sthr[gi+3];

    // ---- single screened exact pass: top-4 + >=0.7 bits (R11 loop) ----
    u64 T0[4] = {0,0,0,0}, T1[4] = {0,0,0,0}, T2[4] = {0,0,0,0}, T3[4] = {0,0,0,0};
    u32 h0 = 0, h1 = 0, h2 = 0, h3 = 0;
    u32 bit = 1u;
    for (int j = lane; j < acnt; j += 64, bit <<= 1) {
      float4 x = sxy[j];
      float aarea = (x.z - x.x) * (x.w - x.y);
      float i0, u0, i1, u1, i2, u2, i3, u3;
      iou_parts(x.x, x.y, x.z, x.w, aarea, g0x0, g0y0, g0x1, g0y1, g0a, i0, u0);
      iou_parts(x.x, x.y, x.z, x.w, aarea, g1x0, g1y0, g1x1, g1y1, g1a, i1, u1);
      iou_parts(x.x, x.y, x.z, x.w, aarea, g2x0, g2y0, g2x1, g2y1, g2a, i2, u2);
      iou_parts(x.x, x.y, x.z, x.w, aarea, g3x0, g3y0, g3x1, g3y1, g3a, i3, u3);
      u32 ni = ~(u32)(base + j);
      bool s0 = (i0 >= t0 * u0), s1 = (i1 >= t1 * u1);
      bool s2 = (i2 >= t2 * u2), s3 = (i3 >= t3 * u3);
      if (__ballot(s0)) {
        float v = 0.0f;
        if (s0) { v = i0 / u0; if (v >= 0.7f) m |= bit; }
        u32 vb = __float_as_uint(v);
        bool ins = s0 && (vb >= h0);
        if (__ballot(ins)) {
          if (ins) top4_insert(T0, ((u64)vb << 32) | (u64)ni);
          h0 = (u32)(T0[3] >> 32);
        }
      }
      if (__ballot(s1)) {
        float v = 0.0f;
        if (s1) { v = i1 / u1; if (v >= 0.7f) m |= bit; }
        u32 vb = __float_as_uint(v);
        bool ins = s1 && (vb >= h1);
        if (__ballot(ins)) {
          if (ins) top4_insert(T1, ((u64)vb << 32) | (u64)ni);
          h1 = (u32)(T1[3] >> 32);
        }
      }
      if (__ballot(s2)) {
        float v = 0.0f;
        if (s2) { v = i2 / u2; if (v >= 0.7f) m |= bit; }
        u32 vb = __float_as_uint(v);
        bool ins = s2 && (vb >= h2);
        if (__ballot(ins)) {
          if (ins) top4_insert(T2, ((u64)vb << 32) | (u64)ni);
          h2 = (u32)(T2[3] >> 32);
        }
      }
      if (__ballot(s3)) {
        float v = 0.0f;
        if (s3) { v = i3 / u3; if (v >= 0.7f) m |= bit; }
        u32 vb = __float_as_uint(v);
        bool ins = s3 && (vb >= h3);
        if (__ballot(ins)) {
          if (ins) top4_insert(T3, ((u64)vb << 32) | (u64)ni);
          h3 = (u32)(T3[3] >> 32);
        }
      }
    }
    wave_merge_top4(T0);
    wave_merge_top4(T1);
    wave_merge_top4(T2);
    wave_merge_top4(T3);
    if (lane == 0) {
      u64* dst = partial + (((size_t)b * NS + s) * G_N + gi) * 4;
      #pragma unroll
      for (int k = 0; k < 4; k++) {
        dst[k] = T0[k]; dst[4 + k] = T1[k]; dst[8 + k] = T2[k]; dst[12 + k] = T3[k];
      }
    }
  }

  __syncthreads();      // all waves done reading sxy (wm aliases it)
  wm[t] = m;
  __syncthreads();
  // wave 0: full OR over all 8 wave masks -> one pos bitmap; pop bits for
  // hist + npos (dedup across gts inherent in the OR).
  if (wave == 0) {
    u32 mc = 0;
    #pragma unroll
    for (int w = 0; w < 8; w++) mc |= wm[w * 64 + lane];
    u64* posH = posA + (size_t)b * NWORD + s * WPS;
    for (int k = 0; k < WPS; k++) {
      u64 bal = __ballot((mc >> k) & 1u);
      if (lane == 0) posH[k] = bal;    // plain store — every word covered exactly once
    }
    // hist + npos for this slice's pos anchors
    u32 k0, k1; image_key(b, k0, k1);
    u32 c = (u32)__popc(mc);
    u32 mm = mc;
    while (mm) {
      int k = __ffs((int)mm) - 1; mm &= mm - 1;
      u32 a = (u32)(base + k * 64 + lane);
      atomicAdd(&hist[b * 4096 + (rbits_for(k0, k1, a) >> 20)], 1u);
    }
    #pragma unroll
    for (int off = 32; off >= 1; off >>= 1) c += __shfl_xor(c, off);
    if (lane == 0 && c) atomicAdd(&npos[b], c);
  }
}

// ---------------- Kernel 2: merge partials -> top4; lq anchors -> posA (+hist) ----------------
__launch_bounds__(64)
__global__ void k_top4_merge(const u64* __restrict__ partial, u64* __restrict__ top4,
                             u64* __restrict__ posA,
                             u32* __restrict__ hist, u32* __restrict__ npos) {
  const int b = blockIdx.y, g = blockIdx.x, lane = threadIdx.x;
  const u64* pb = partial + ((size_t)b * NS * G_N + g) * 4;
  u64 keys[7];                       // NS*4 = 392 -> <= 7 per lane
  int nk = 0;
  for (int i = lane; i < NS * 4; i += 64)
    keys[nk++] = pb[(size_t)(i >> 2) * (G_N * 4) + (i & 3)];
  u64 top[4] = {0ull, 0ull, 0ull, 0ull};
  for (int q = 0; q < nk; q++) top4_insert(top, keys[q]);
  wave_merge_top4(top);
  if (lane == 0) {
    u64* dst = top4 + ((size_t)b * G_N + g) * 4;
    #pragma unroll
    for (int k = 0; k < 4; k++) dst[k] = top[k];
  }
  // low-quality matches: every partial entry whose value bits == hq bits.
  // atomicOr's old value dedups hist/npos across all setters (incl. k_main).
  u32 hqb = (u32)(__shfl(top[0], 0) >> 32);
  u32 kk0, kk1; image_key(b, kk0, kk1);
  for (int q = 0; q < nk; q++) {
    u64 key = keys[q];
    u32 aidx = ~(u32)key;
    if ((u32)(key >> 32) == hqb && aidx < A_N) {
      u64 bit = 1ull << (aidx & 63);
      u64 old = atomicOr(&posA[(size_t)b * NWORD + (aidx >> 6)], bit);
      if (!(old & bit)) {
        atomicAdd(&hist[b * 4096 + (rbits_for(kk0, kk1, aidx) >> 20)], 1u);
        atomicAdd(&npos[b], 1u);
      }
    }
  }
}

// ---------------- Kernel 3: local bin selection + collect fine candidates ----------------
// grid (NS, B).
__launch_bounds__(256)
__global__ void k_collect(const u64* __restrict__ posA,
                          const u32* __restrict__ npos, const u32* __restrict__ hist,
                          int2* __restrict__ binsel,
                          u32* __restrict__ fine, u32* __restrict__ fcnt) {
  const int b = blockIdx.y;
  const int t = threadIdx.x;
  __shared__ u32 red[256];
  __shared__ int sbin;

  const u32* hb = hist + b * 4096;
  u32 local = 0;
  for (int j = 0; j < 16; j++) local += hb[t * 16 + j];
  red[t] = local;
  __syncthreads();
  if (t == 0) {
    if (npos[b] <= MAX_POS) {
      sbin = -1;
      binsel[b] = make_int2(-1, 0);          // duplicate identical writes across blocks
    } else {
      u32 cum = 0; int chunk = 0;
      for (int i = 0; i < 256; i++) {
        if (cum + red[i] >= MAX_POS) { chunk = i; break; }
        cum += red[i];
      }
      int tb = chunk * 16; u32 before = cum;
      for (int j = 0; j < 16; j++) {
        u32 h = hb[chunk * 16 + j];
        if (before + h >= MAX_POS) { tb = chunk * 16 + j; break; }
        before += h;
      }
      sbin = tb;
      binsel[b] = make_int2(tb, (int)before);
    }
  }
  __syncthreads();
  const int stb = sbin;
  if (stb < 0) return;

  u32 k0, k1; image_key(b, k0, k1);
  const int a0 = blockIdx.x * AS;
  const u64* pa = posA + (size_t)b * NWORD;
  for (int j = t; j < AS; j += 256) {
    int a = a0 + j;
    if (a >= A_N) break;
    if (!((pa[a >> 6] >> (a & 63)) & 1ull)) continue;
    u32 rb = rbits_for(k0, k1, (u32)a);
    if ((int)(rb >> 20) != stb) continue;
    u32 idx = atomicAdd(&fcnt[b], 1u);
    if (idx < FINE_CAP) fine[b * FINE_CAP + idx] = (((rb >> 9) & 0x7FFu) << 18) | (u32)a;
  }
}

// ---------------- Kernel 4: local Tstar + per-gt counts of selected ----------------
// grid (NS, B).
__launch_bounds__(256)
__global__ void k_count(const float4* __restrict__ anchors, const float4* __restrict__ gt,
                        const u64* __restrict__ posA,
                        const int2* __restrict__ binsel, const u32* __restrict__ fine,
                        const u32* __restrict__ fcnt, u32* __restrict__ cnt) {
  const int b = blockIdx.y;
  const int t = threadIdx.x;
  __shared__ float sg[5][64];
  __shared__ u64 sT;

  if (t < 64) {
    float x0, y0, x1, y1, ar;
    conv_box(gt[(size_t)b * G_N + t], x0, y0, x1, y1, ar);
    sg[0][t] = x0; sg[1][t] = y0; sg[2][t] = x1; sg[3][t] = y1; sg[4][t] = ar;
    // wave 0: compute Tstar locally (binary search over the small fine list)
    int2 bs = binsel[b];
    u64 T = ~0ull;
    if (bs.x >= 0) {
      const int m = min((int)fcnt[b], FINE_CAP);
      const u32 need = (u32)(MAX_POS - bs.y);   // >= 1
      const u32* fb = fine + b * FINE_CAP;
      u32 lo = 0, hi = (1u << 29) - 1;
      while (lo < hi) {
        u32 mid = lo + ((hi - lo) >> 1);
        u32 c = 0;
        for (int j = t; j < m; j += 64) c += (fb[j] <= mid) ? 1u : 0u;
        #pragma unroll
        for (int off = 32; off >= 1; off >>= 1) c += __shfl_xor(c, off);
        if (c >= need) hi = mid; else lo = mid + 1;   // uniform across wave
      }
      T = ((u64)(u32)bs.x << 29) | (u64)lo;   // 41-bit threshold
    }
    if (t == 0) sT = T;
  }
  __syncthreads();

  u32 k0, k1; image_key(b, k0, k1);
  const u64 T = sT;
  const int a0 = blockIdx.x * AS;
  const u64* pa = posA + (size_t)b * NWORD;
  const float4* ab = anchors + (size_t)b * A_N;
  for (int j = t; j < AS; j += 256) {
    int a = a0 + j;
    if (a >= A_N) break;
    if (!((pa[a >> 6] >> (a & 63)) & 1ull)) continue;
    if (T != ~0ull) {
      u32 rb = rbits_for(k0, k1, (u32)a);
      if (((((u64)(rb >> 9)) << 18) | (u64)(u32)a) > T) continue;
    }
    float ax0, ay0, ax1, ay1, aar;
    conv_box(ab[a], ax0, ay0, ax1, ay1, aar);
    float bv = -1.0f; int g0 = 0;
    for (int g = 0; g < 64; g++) {
      float v = iou_pair(ax0, ay0, ax1, ay1, aar,
                         sg[0][g], sg[1][g], sg[2][g], sg[3][g], sg[4][g]);
      if (v > bv) { bv = v; g0 = g; }   // strict > = first max (jnp.argmax)
    }
    atomicAdd(&cnt[b * G_N + g0], 1u);
  }
}

// ---------------- Kernel 5: output ----------------
__launch_bounds__(64)
__global__ void k_out(const u64* __restrict__ top4, const u32* __restrict__ cnt,
                      float* __restrict__ out, int sec) {
  const int b = blockIdx.x;
  const int g = threadIdx.x;   // 64 threads
  const u32 c = min(cnt[b * G_N + g], (u32)K_TOP);
  const u64* t4 = top4 + ((size_t)b * G_N + g) * 4;
  #pragma unroll
  for (int k = 0; k < 4; k++) {
    u64 key = t4[k];
    u32 fb = (u32)(key >> 32);
    u32 aidx = ~(u32)key;
    bool valid = (u32)k < c;
    int o = b * (G_N * K_TOP) + g * K_TOP + k;
    out[0 * sec + o] = valid ? (float)aidx : -1.0f;          // pr_inds
    out[1 * sec + o] = valid ? (float)g : -1.0f;             // gt_inds
    out[2 * sec + o] = valid ? 1.0f : 0.0f;                  // valid mask
    out[3 * sec + o] = valid ? __uint_as_float(fb) : 0.0f;   // topk ious
  }
}

extern "C" void kernel_launch(void* const* d_in, const int* in_sizes, int n_in,
                              void* d_out, int out_size, void* d_ws, size_t ws_size,
                              hipStream_t stream) {
  const float4* anchors = (const float4*)d_in[0];  // [B, A, 4] cxcywh
  const float4* gt      = (const float4*)d_in[1];  // [B, G, 4] cxcywh
  float* out = (float*)d_out;                      // 4 x [B, G*K] concatenated

  // Layout — 1,988,672 B, UNDER the R5..R14-proven 2,025,536 B extent:
  //   top4     @ 0          (16,384)  [written k_top4_merge, read k_out]
  //   partial  @ 16,384     (1,605,632) — dead after k_top4_merge;
  //     aliases (written only in dispatches >= 3):
  //       fine   @ 16,384    (131,072)  [k_collect]
  //       binsel @ 147,456   (64)       [k_collect]
  //   posA     @ 1,622,016  (200,704)  [single bitmap; fully ballot-stored]
  //   hist     @ 1,822,720  (131,072)  [zeroed by k_thresh; live from k_main]
  //   small    @ 1,953,792  (2,112): npos(32) fcnt(32) cnt(2,048)
  //            [zeroed by k_thresh s==0,half==0 blocks]
  //   thr_part @ 1,955,904  (32,768)  [written k_thresh, read k_main]
  char* ws = (char*)d_ws;
  u64*  top4    = (u64*)(ws);
  u64*  partial = (u64*)(ws + 16384);
  u32*  fine    = (u32*)(ws + 16384);
  int2* binsel  = (int2*)(ws + 147456);
  u64*  posA    = (u64*)(ws + 1622016);
  u32*  hist    = (u32*)(ws + 1822720);
  u32*  npos    = (u32*)(ws + 1953792);
  u32*  fcnt    = (u32*)(ws + 1953824);
  u32*  cnt     = (u32*)(ws + 1953856);
  u32*  thr_prt = (u32*)(ws + 1955904);

  int sec = out_size / 4;  // 2048 = B*G*K

  k_thresh    <<<dim3(SUB_SL, B_IMG, 2), 512, 0, stream>>>(anchors, gt, thr_prt, hist, npos, fcnt, cnt);
  k_main      <<<dim3(NS, B_IMG), 512, 0, stream>>>(anchors, gt, thr_prt, partial, posA, hist, npos);
  k_top4_merge<<<dim3(G_N, B_IMG), 64, 0, stream>>>(partial, top4, posA, hist, npos);
  k_collect   <<<dim3(NS, B_IMG), 256, 0, stream>>>(posA, npos, hist, binsel, fine, fcnt);
  k_count     <<<dim3(NS, B_IMG), 256, 0, stream>>>(anchors, gt, posA, binsel, fine, fcnt, cnt);
  k_out       <<<dim3(B_IMG), 64, 0, stream>>>(top4, cnt, out, sec);
}

// Round 10
// 250.379 us; speedup vs baseline: 1.1403x; 1.0028x over previous
//
#include <hip/hip_runtime.h>
#include <stdint.h>

// Stage1Assigner (RPN matcher + subsample + top-k per GT) for MI355X.
// B=8 images, A=200000 anchors, G=64 GTs, K=4, thresholds 0.3/0.7, 128 max pos.
//
// PRNG: JAX threefry, jax_threefry_partitionable=True:
//   keys[b] = threefry2x32((0,42),(0,b));  bits[a] = y0^y1 of threefry2x32(key_b,(0,a))
// Selection of 128 positives = 128 lexicographically smallest (bits>>9, a).
//
// R17 vs R16/R15: R16's hipLaunchCooperativeKernel silently failed under the
// harness's hipGraph capture (output stayed memset-zero; absmax = max anchor
// index) -> cooperative fusion is OFF THE TABLE. R17 reverts to the proven
// R15 5-kernel structure and removes ONE dispatch boundary safely:
//   * k_out folded into k_count via a RANK TRICK: r = atomicAdd(&cnt[g0],1)
//     is this selected anchor's unique rank among gt g0's selections; slot
//     (g0, r<4) gets payload top4[b][g0][r] (written by the earlier k_merge
//     dispatch). Ranks unique -> each slot written once -> exactly
//     min(cnt,4) valid slots, identical to k_out's k < min(cnt,4).
//   * invalid defaults (pr=-1, gt=-1, mask=0, iou=0) written by k_thresh
//     (first dispatch, 2048 slots) so defaults don't rely on harness memset.
// 6 dispatches -> 5. All exact comparisons identical to R5..R15 ->
// bit-identical output.
//
// k_main: R11 4-ballot loop (fastest measured; R13 gate and R14 split both
// regressed). Epilogue ORs 8 wave masks -> single pos bitmap + inline
// threefry hist + npos.
//
// Screen: thrG[gt] = max over 16 sampled 1024-anchor sub-slices of the
// 4th-of-lane-maxima of approx q = inter*rcp(uni) (lower bound on the global
// 4th-largest). t~ = bits(min(thrG - 16ulp, 0.7f - 8ulp)) - 8ulp  (rcp err
// <= ~2.5 ulp << 16-ulp slack; 8-ulp product margin covers binade edges;
// denormal flush -> never-skip; thrG=0 -> screen passes everything -> safe).
// Value-0 fake entries (masked lanes insert vb=0 early) are displaced
// whenever a gt has >=4 anchors with iou>0 globally (guaranteed here).
//
// IoU is fp-contract(off) IEEE per-op: identical bits across all passes and
// matches XLA per-HLO rounding.

#pragma clang fp contract(off)

#define B_IMG 8
#define A_N 200000
#define G_N 64
#define K_TOP 4
#define MAX_POS 128
#define FINE_CAP 4096
#define AS 2048
#define NS 98            // ceil(200000/2048)
#define SUB_SL 16        // sampled sub-slices (1024 anchors each)
#define SUB_AS 1024
#define WPS 32           // u64 ballot words per slice
#define NWORD 3136       // NS*WPS words of pos bits per image

typedef unsigned long long u64;
typedef unsigned int u32;

__device__ __forceinline__ u32 rotl32(u32 v, int n) { return (v << n) | (v >> (32 - n)); }

__device__ __forceinline__ void tf_round(u32& x0, u32& x1, int r) {
  x0 += x1; x1 = rotl32(x1, r); x1 ^= x0;
}

__device__ __forceinline__ void threefry2x32(u32 k0, u32 k1, u32& x0, u32& x1) {
  u32 ks2 = 0x1BD11BDAu ^ k0 ^ k1;
  x0 += k0; x1 += k1;
  tf_round(x0,x1,13); tf_round(x0,x1,15); tf_round(x0,x1,26); tf_round(x0,x1,6);
  x0 += k1; x1 += ks2 + 1u;
  tf_round(x0,x1,17); tf_round(x0,x1,29); tf_round(x0,x1,16); tf_round(x0,x1,24);
  x0 += ks2; x1 += k0 + 2u;
  tf_round(x0,x1,13); tf_round(x0,x1,15); tf_round(x0,x1,26); tf_round(x0,x1,6);
  x0 += k0; x1 += k1 + 3u;
  tf_round(x0,x1,17); tf_round(x0,x1,29); tf_round(x0,x1,16); tf_round(x0,x1,24);
  x0 += k1; x1 += ks2 + 4u;
  tf_round(x0,x1,13); tf_round(x0,x1,15); tf_round(x0,x1,26); tf_round(x0,x1,6);
  x0 += ks2; x1 += k0 + 5u;
}

__device__ __forceinline__ void image_key(int b, u32& kb0, u32& kb1) {
  u32 x0 = 0u, x1 = (u32)b;
  threefry2x32(0u, 42u, x0, x1);
  kb0 = x0; kb1 = x1;
}

__device__ __forceinline__ u32 rbits_for(u32 k0, u32 k1, u32 a) {
  u32 x0 = 0u, x1 = a;
  threefry2x32(k0, k1, x0, x1);
  return x0 ^ x1;
}

__device__ __forceinline__ void conv_box(float4 bx, float& x0, float& y0,
                                         float& x1, float& y1, float& area) {
  #pragma clang fp contract(off)
  x0 = bx.x - 0.5f * bx.z;
  y0 = bx.y - 0.5f * bx.w;
  x1 = bx.x + 0.5f * bx.z;
  y1 = bx.y + 0.5f * bx.w;
  area = (x1 - x0) * (y1 - y0);
}

__device__ __forceinline__ float iou_pair(float ax0, float ay0, float ax1, float ay1, float aarea,
                                          float gx0, float gy0, float gx1, float gy1, float garea) {
  #pragma clang fp contract(off)
  float ltx = fmaxf(gx0, ax0), lty = fmaxf(gy0, ay0);
  float rbx = fminf(gx1, ax1), rby = fminf(gy1, ay1);
  float w = fmaxf(rbx - ltx, 0.0f), h = fmaxf(rby - lty, 0.0f);
  float inter = w * h;
  float uni = (garea + aarea) - inter;
  return inter / uni;
}

// inter/uni only (no division) — same rounding sequence as iou_pair's prefix.
__device__ __forceinline__ void iou_parts(float ax0, float ay0, float ax1, float ay1, float aarea,
                                          float gx0, float gy0, float gx1, float gy1, float garea,
                                          float& inter, float& uni) {
  #pragma clang fp contract(off)
  float ltx = fmaxf(gx0, ax0), lty = fmaxf(gy0, ay0);
  float rbx = fminf(gx1, ax1), rby = fminf(gy1, ay1);
  float w = fmaxf(rbx - ltx, 0.0f), h = fmaxf(rby - lty, 0.0f);
  inter = w * h;
  uni = (garea + aarea) - inter;
}

__device__ __forceinline__ void top4_insert(u64 (&top)[4], u64 key) {
  if (key > top[3]) {
    if (key > top[0])      { top[3]=top[2]; top[2]=top[1]; top[1]=top[0]; top[0]=key; }
    else if (key > top[1]) { top[3]=top[2]; top[2]=top[1]; top[1]=key; }
    else if (key > top[2]) { top[3]=top[2]; top[2]=key; }
    else                   { top[3]=key; }
  }
}

__device__ __forceinline__ void wave_merge_top4(u64 (&top)[4]) {
  for (int off = 32; off >= 1; off >>= 1) {
    u64 o[4];
    #pragma unroll
    for (int k = 0; k < 4; k++) o[k] = __shfl_down(top[k], (unsigned)off);
    u64 m[4]; int i = 0, j = 0;
    #pragma unroll
    for (int k = 0; k < 4; k++) m[k] = (top[i] >= o[j]) ? top[i++] : o[j++];
    #pragma unroll
    for (int k = 0; k < 4; k++) top[k] = m[k];
  }
}

__device__ __forceinline__ void wave_merge_top4_u32(u32 (&top)[4]) {
  for (int off = 32; off >= 1; off >>= 1) {
    u32 o[4];
    #pragma unroll
    for (int k = 0; k < 4; k++) o[k] = __shfl_down(top[k], (unsigned)off);
    u32 m[4]; int i = 0, j = 0;
    #pragma unroll
    for (int k = 0; k < 4; k++) m[k] = (top[i] >= o[j]) ? top[i++] : o[j++];
    #pragma unroll
    for (int k = 0; k < 4; k++) top[k] = m[k];
  }
}

// conservative screen threshold: t~ = bitcast(max(tau,8)-8)  (tau = f32 bits)
__device__ __forceinline__ float screen_thresh(u32 tau) {
  u32 tb = (tau > 8u) ? (tau - 8u) : 0u;
  return __uint_as_float(tb);
}

// ---------------- Kernel 0: sampled thresholds + zero state + out defaults ----------------
// grid (SUB_SL, B, 2); block 512 = 8 waves; wave w handles gt-group
// half*8 + w (ONE group -> 16 j-iters/wave). Sub-slice s = anchors
// [s*1024, s*1024+1024) — total sampled set identical to R11..R15 (0..16383).
// hist zeroed by first 32768 linear threads; out defaults by first 2048.
__launch_bounds__(512, 4)
__global__ void k_thresh(const float4* __restrict__ anchors, const float4* __restrict__ gt,
                         u32* __restrict__ thr_part, u32* __restrict__ hist,
                         u32* __restrict__ npos, u32* __restrict__ fcnt,
                         u32* __restrict__ cnt,
                         float* __restrict__ out, int sec) {
  const int s = blockIdx.x;        // 0..SUB_SL-1
  const int b = blockIdx.y;
  const int half = blockIdx.z;     // gt half
  const int t = threadIdx.x;
  const int wave = t >> 6, lane = t & 63;

  __shared__ float4 sxy[SUB_AS];
  __shared__ float  sg[5][32];

  // zero hist + write invalid output defaults (k_count later overwrites the
  // valid slots; this dispatch precedes it on the stream)
  {
    int lid = ((half * B_IMG + b) * SUB_SL + s) * 512 + t;
    if (lid < B_IMG * 4096) hist[lid] = 0;
    if (lid < B_IMG * G_N * K_TOP) {
      out[0 * sec + lid] = -1.0f;
      out[1 * sec + lid] = -1.0f;
      out[2 * sec + lid] = 0.0f;
      out[3 * sec + lid] = 0.0f;
    }
  }
  if (s == 0 && half == 0) {
    if (t < 64) cnt[b * G_N + t] = 0;
    if (t == 0) { fcnt[b] = 0; npos[b] = 0; }
  }

  const int base = s * SUB_AS;
  const float4* ab = anchors + (size_t)b * A_N + base;

  for (int j = t; j < SUB_AS; j += 512) {
    float x0, y0, x1, y1, ar;
    conv_box(ab[j], x0, y0, x1, y1, ar);
    sxy[j] = make_float4(x0, y0, x1, y1);
  }
  if (t < 32) {
    float x0, y0, x1, y1, ar;
    conv_box(gt[(size_t)b * G_N + half * 32 + t], x0, y0, x1, y1, ar);
    sg[0][t] = x0; sg[1][t] = y0; sg[2][t] = x1; sg[3][t] = y1; sg[4][t] = ar;
  }
  __syncthreads();

  {
    const int gi = wave * 4;       // local gt index within this half
    const float g0x0 = sg[0][gi],   g0y0 = sg[1][gi],   g0x1 = sg[2][gi],   g0y1 = sg[3][gi],   g0a = sg[4][gi];
    const float g1x0 = sg[0][gi+1], g1y0 = sg[1][gi+1], g1x1 = sg[2][gi+1], g1y1 = sg[3][gi+1], g1a = sg[4][gi+1];
    const float g2x0 = sg[0][gi+2], g2y0 = sg[1][gi+2], g2x1 = sg[2][gi+2], g2y1 = sg[3][gi+2], g2a = sg[4][gi+2];
    const float g3x0 = sg[0][gi+3], g3y0 = sg[1][gi+3], g3x1 = sg[2][gi+3], g3y1 = sg[3][gi+3], g3a = sg[4][gi+3];

    u32 q0 = 0, q1 = 0, q2 = 0, q3 = 0;
    for (int j = lane; j < SUB_AS; j += 64) {
      float4 x = sxy[j];
      float aarea = (x.z - x.x) * (x.w - x.y);
      float i0, u0, i1, u1, i2, u2, i3, u3;
      iou_parts(x.x, x.y, x.z, x.w, aarea, g0x0, g0y0, g0x1, g0y1, g0a, i0, u0);
      iou_parts(x.x, x.y, x.z, x.w, aarea, g1x0, g1y0, g1x1, g1y1, g1a, i1, u1);
      iou_parts(x.x, x.y, x.z, x.w, aarea, g2x0, g2y0, g2x1, g2y1, g2a, i2, u2);
      iou_parts(x.x, x.y, x.z, x.w, aarea, g3x0, g3y0, g3x1, g3y1, g3a, i3, u3);
      q0 = max(q0, __float_as_uint(i0 * __builtin_amdgcn_rcpf(u0)));
      q1 = max(q1, __float_as_uint(i1 * __builtin_amdgcn_rcpf(u1)));
      q2 = max(q2, __float_as_uint(i2 * __builtin_amdgcn_rcpf(u2)));
      q3 = max(q3, __float_as_uint(i3 * __builtin_amdgcn_rcpf(u3)));
    }
    u32 Q0[4] = {q0,0,0,0}, Q1[4] = {q1,0,0,0}, Q2[4] = {q2,0,0,0}, Q3[4] = {q3,0,0,0};
    wave_merge_top4_u32(Q0);
    wave_merge_top4_u32(Q1);
    wave_merge_top4_u32(Q2);
    wave_merge_top4_u32(Q3);
    if (lane == 0) {
      u32* dst = thr_part + ((size_t)b * SUB_SL + s) * G_N + half * 32 + gi;
      dst[0] = Q0[3]; dst[1] = Q1[3]; dst[2] = Q2[3]; dst[3] = Q3[3];
    }
  }
}

// ---------------- Kernel 1: screened exact pass + pos bitmap + hist ----------------
// grid (NS, B); block 512 = 8 waves; wave w handles gt-groups {2w, 2w+1}.
// Inner loop: exact R11 formulation (fastest measured; no spill).
// Epilogue: OR all 8 wave masks -> ONE pos bitmap; wave 0 pops bits for
// hist + npos.
// launch_bounds (512,4): VGPR cap — allocator lands at 56, no spill.
__launch_bounds__(512, 4)
__global__ void k_main(const float4* __restrict__ anchors, const float4* __restrict__ gt,
                       const u32* __restrict__ thr_part,
                       u64* __restrict__ partial, u64* __restrict__ posA,
                       u32* __restrict__ hist, u32* __restrict__ npos) {
  const int s = blockIdx.x;
  const int b = blockIdx.y;
  const int t = threadIdx.x;
  const int wave = t >> 6, lane = t & 63;

  __shared__ float4 sxy[AS];        // converted xyxy; reused as wm after gp loop
  __shared__ float  sg[5][64];
  __shared__ float  sthr[64];       // per-gt screen thresholds (slack applied)
  u32* wm = (u32*)sxy;

  const int base = s * AS;
  const int acnt = min(AS, A_N - base);
  const float4* ab = anchors + (size_t)b * A_N + base;

  for (int j = t; j < acnt; j += 512) {
    float x0, y0, x1, y1, ar;
    conv_box(ab[j], x0, y0, x1, y1, ar);
    sxy[j] = make_float4(x0, y0, x1, y1);
  }
  if (t < 64) {
    float x0, y0, x1, y1, ar;
    conv_box(gt[(size_t)b * G_N + t], x0, y0, x1, y1, ar);
    sg[0][t] = x0; sg[1][t] = y0; sg[2][t] = x1; sg[3][t] = y1; sg[4][t] = ar;
    // global sampled threshold for gt t: max over the SUB_SL sub-slice Q4s,
    // then the standard 16-ulp rcp slack + (0.7f - 8ulp) cap + 8-ulp margin.
    u32 mx = 0;
    for (int ss = 0; ss < SUB_SL; ss++)
      mx = max(mx, thr_part[((size_t)b * SUB_SL + ss) * G_N + t]);
    const u32 L7 = 0x3F333333u - 8u;   // 0.7f bits - 8 ulp
    sthr[t] = screen_thresh(min(mx > 16u ? mx - 16u : 0u, L7));
  }
  __syncthreads();

  u32 m = 0;   // bit k: anchor base+64k+lane has iou>=0.7 vs any of this wave's gts
  for (int gg = 0; gg < 2; gg++) {
    const int gp = wave * 2 + gg;      // 0..15
    const int gi = gp * 4;             // global gt index of group start
    const float g0x0 = sg[0][gi],   g0y0 = sg[1][gi],   g0x1 = sg[2][gi],   g0y1 = sg[3][gi],   g0a = sg[4][gi];
    const float g1x0 = sg[0][gi+1], g1y0 = sg[1][gi+1], g1x1 = sg[2][gi+1], g1y1 = sg[3][gi+1], g1a = sg[4][gi+1];
    const float g2x0 = sg[0][gi+2], g2y0 = sg[1][gi+2], g2x1 = sg[2][gi+2], g2y1 = sg[3][gi+2], g2a = sg[4][gi+2];
    const float g3x0 = sg[0][gi+3], g3y0 = sg[1][gi+3], g3x1 = sg[2][gi+3], g3y1 = sg[3][gi+3], g3a = sg[4][gi+3];
    const float t0 = sthr[gi], t1 = sthr[gi+1], t2 = sthr[gi+2], t3 = sthr[gi+3];

    // ---- single screened exact pass: top-4 + >=0.7 bits (R11 loop) ----
    u64 T0[4] = {0,0,0,0}, T1[4] = {0,0,0,0}, T2[4] = {0,0,0,0}, T3[4] = {0,0,0,0};
    u32 h0 = 0, h1 = 0, h2 = 0, h3 = 0;
    u32 bit = 1u;
    for (int j = lane; j < acnt; j += 64, bit <<= 1) {
      float4 x = sxy[j];
      float aarea = (x.z - x.x) * (x.w - x.y);
      float i0, u0, i1, u1, i2, u2, i3, u3;
      iou_parts(x.x, x.y, x.z, x.w, aarea, g0x0, g0y0, g0x1, g0y1, g0a, i0, u0);
      iou_parts(x.x, x.y, x.z, x.w, aarea, g1x0, g1y0, g1x1, g1y1, g1a, i1, u1);
      iou_parts(x.x, x.y, x.z, x.w, aarea, g2x0, g2y0, g2x1, g2y1, g2a, i2, u2);
      iou_parts(x.x, x.y, x.z, x.w, aarea, g3x0, g3y0, g3x1, g3y1, g3a, i3, u3);
      u32 ni = ~(u32)(base + j);
      bool s0 = (i0 >= t0 * u0), s1 = (i1 >= t1 * u1);
      bool s2 = (i2 >= t2 * u2), s3 = (i3 >= t3 * u3);
      if (__ballot(s0)) {
        float v = 0.0f;
        if (s0) { v = i0 / u0; if (v >= 0.7f) m |= bit; }
        u32 vb = __float_as_uint(v);
        bool ins = s0 && (vb >= h0);
        if (__ballot(ins)) {
          if (ins) top4_insert(T0, ((u64)vb << 32) | (u64)ni);
          h0 = (u32)(T0[3] >> 32);
        }
      }
      if (__ballot(s1)) {
        float v = 0.0f;
        if (s1) { v = i1 / u1; if (v >= 0.7f) m |= bit; }
        u32 vb = __float_as_uint(v);
        bool ins = s1 && (vb >= h1);
        if (__ballot(ins)) {
          if (ins) top4_insert(T1, ((u64)vb << 32) | (u64)ni);
          h1 = (u32)(T1[3] >> 32);
        }
      }
      if (__ballot(s2)) {
        float v = 0.0f;
        if (s2) { v = i2 / u2; if (v >= 0.7f) m |= bit; }
        u32 vb = __float_as_uint(v);
        bool ins = s2 && (vb >= h2);
        if (__ballot(ins)) {
          if (ins) top4_insert(T2, ((u64)vb << 32) | (u64)ni);
          h2 = (u32)(T2[3] >> 32);
        }
      }
      if (__ballot(s3)) {
        float v = 0.0f;
        if (s3) { v = i3 / u3; if (v >= 0.7f) m |= bit; }
        u32 vb = __float_as_uint(v);
        bool ins = s3 && (vb >= h3);
        if (__ballot(ins)) {
          if (ins) top4_insert(T3, ((u64)vb << 32) | (u64)ni);
          h3 = (u32)(T3[3] >> 32);
        }
      }
    }
    wave_merge_top4(T0);
    wave_merge_top4(T1);
    wave_merge_top4(T2);
    wave_merge_top4(T3);
    if (lane == 0) {
      u64* dst = partial + (((size_t)b * NS + s) * G_N + gi) * 4;
      #pragma unroll
      for (int k = 0; k < 4; k++) {
        dst[k] = T0[k]; dst[4 + k] = T1[k]; dst[8 + k] = T2[k]; dst[12 + k] = T3[k];
      }
    }
  }

  __syncthreads();      // all waves done reading sxy (wm aliases it)
  wm[t] = m;
  __syncthreads();
  // wave 0: full OR over all 8 wave masks -> one pos bitmap; pop bits for
  // hist + npos (dedup across gts inherent in the OR).
  if (wave == 0) {
    u32 mc = 0;
    #pragma unroll
    for (int w = 0; w < 8; w++) mc |= wm[w * 64 + lane];
    u64* posH = posA + (size_t)b * NWORD + s * WPS;
    for (int k = 0; k < WPS; k++) {
      u64 bal = __ballot((mc >> k) & 1u);
      if (lane == 0) posH[k] = bal;    // plain store — every word covered exactly once
    }
    // hist + npos for this slice's pos anchors
    u32 k0, k1; image_key(b, k0, k1);
    u32 c = (u32)__popc(mc);
    u32 mm = mc;
    while (mm) {
      int k = __ffs((int)mm) - 1; mm &= mm - 1;
      u32 a = (u32)(base + k * 64 + lane);
      atomicAdd(&hist[b * 4096 + (rbits_for(k0, k1, a) >> 20)], 1u);
    }
    #pragma unroll
    for (int off = 32; off >= 1; off >>= 1) c += __shfl_xor(c, off);
    if (lane == 0 && c) atomicAdd(&npos[b], c);
  }
}

// ---------------- Kernel 2: merge partials -> top4; lq anchors -> posA (+hist) ----------------
__launch_bounds__(64)
__global__ void k_top4_merge(const u64* __restrict__ partial, u64* __restrict__ top4,
                             u64* __restrict__ posA,
                             u32* __restrict__ hist, u32* __restrict__ npos) {
  const int b = blockIdx.y, g = blockIdx.x, lane = threadIdx.x;
  const u64* pb = partial + ((size_t)b * NS * G_N + g) * 4;
  u64 keys[7];                       // NS*4 = 392 -> <= 7 per lane
  int nk = 0;
  for (int i = lane; i < NS * 4; i += 64)
    keys[nk++] = pb[(size_t)(i >> 2) * (G_N * 4) + (i & 3)];
  u64 top[4] = {0ull, 0ull, 0ull, 0ull};
  for (int q = 0; q < nk; q++) top4_insert(top, keys[q]);
  wave_merge_top4(top);
  if (lane == 0) {
    u64* dst = top4 + ((size_t)b * G_N + g) * 4;
    #pragma unroll
    for (int k = 0; k < 4; k++) dst[k] = top[k];
  }
  // low-quality matches: every partial entry whose value bits == hq bits.
  // atomicOr's old value dedups hist/npos across all setters (incl. k_main).
  u32 hqb = (u32)(__shfl(top[0], 0) >> 32);
  u32 kk0, kk1; image_key(b, kk0, kk1);
  for (int q = 0; q < nk; q++) {
    u64 key = keys[q];
    u32 aidx = ~(u32)key;
    if ((u32)(key >> 32) == hqb && aidx < A_N) {
      u64 bit = 1ull << (aidx & 63);
      u64 old = atomicOr(&posA[(size_t)b * NWORD + (aidx >> 6)], bit);
      if (!(old & bit)) {
        atomicAdd(&hist[b * 4096 + (rbits_for(kk0, kk1, aidx) >> 20)], 1u);
        atomicAdd(&npos[b], 1u);
      }
    }
  }
}

// ---------------- Kernel 3: local bin selection + collect fine candidates ----------------
// grid (NS, B).
__launch_bounds__(256)
__global__ void k_collect(const u64* __restrict__ posA,
                          const u32* __restrict__ npos, const u32* __restrict__ hist,
                          int2* __restrict__ binsel,
                          u32* __restrict__ fine, u32* __restrict__ fcnt) {
  const int b = blockIdx.y;
  const int t = threadIdx.x;
  __shared__ u32 red[256];
  __shared__ int sbin;

  const u32* hb = hist + b * 4096;
  u32 local = 0;
  for (int j = 0; j < 16; j++) local += hb[t * 16 + j];
  red[t] = local;
  __syncthreads();
  if (t == 0) {
    if (npos[b] <= MAX_POS) {
      sbin = -1;
      binsel[b] = make_int2(-1, 0);          // duplicate identical writes across blocks
    } else {
      u32 cum = 0; int chunk = 0;
      for (int i = 0; i < 256; i++) {
        if (cum + red[i] >= MAX_POS) { chunk = i; break; }
        cum += red[i];
      }
      int tb = chunk * 16; u32 before = cum;
      for (int j = 0; j < 16; j++) {
        u32 h = hb[chunk * 16 + j];
        if (before + h >= MAX_POS) { tb = chunk * 16 + j; break; }
        before += h;
      }
      sbin = tb;
      binsel[b] = make_int2(tb, (int)before);
    }
  }
  __syncthreads();
  const int stb = sbin;
  if (stb < 0) return;

  u32 k0, k1; image_key(b, k0, k1);
  const int a0 = blockIdx.x * AS;
  const u64* pa = posA + (size_t)b * NWORD;
  for (int j = t; j < AS; j += 256) {
    int a = a0 + j;
    if (a >= A_N) break;
    if (!((pa[a >> 6] >> (a & 63)) & 1ull)) continue;
    u32 rb = rbits_for(k0, k1, (u32)a);
    if ((int)(rb >> 20) != stb) continue;
    u32 idx = atomicAdd(&fcnt[b], 1u);
    if (idx < FINE_CAP) fine[b * FINE_CAP + idx] = (((rb >> 9) & 0x7FFu) << 18) | (u32)a;
  }
}

// ---------------- Kernel 4: Tstar + per-gt rank -> direct output ----------------
// grid (NS, B). Rank trick: r = atomicAdd(&cnt[g0],1) is this selected
// anchor's unique rank for gt g0; slot (g0, r<4) gets payload top4[b][g0][r].
// Exactly min(cnt,4) slots become valid == old k_out semantics. Invalid
// defaults were written by k_thresh (earlier dispatch).
__launch_bounds__(256)
__global__ void k_count(const float4* __restrict__ anchors, const float4* __restrict__ gt,
                        const u64* __restrict__ posA,
                        const int2* __restrict__ binsel, const u32* __restrict__ fine,
                        const u32* __restrict__ fcnt, u32* __restrict__ cnt,
                        const u64* __restrict__ top4,
                        float* __restrict__ out, int sec) {
  const int b = blockIdx.y;
  const int t = threadIdx.x;
  __shared__ float sg[5][64];
  __shared__ u64 sT;

  if (t < 64) {
    float x0, y0, x1, y1, ar;
    conv_box(gt[(size_t)b * G_N + t], x0, y0, x1, y1, ar);
    sg[0][t] = x0; sg[1][t] = y0; sg[2][t] = x1; sg[3][t] = y1; sg[4][t] = ar;
    // wave 0: compute Tstar locally (binary search over the small fine list)
    int2 bs = binsel[b];
    u64 T = ~0ull;
    if (bs.x >= 0) {
      const int m = min((int)fcnt[b], FINE_CAP);
      const u32 need = (u32)(MAX_POS - bs.y);   // >= 1
      const u32* fb = fine + b * FINE_CAP;
      u32 lo = 0, hi = (1u << 29) - 1;
      while (lo < hi) {
        u32 mid = lo + ((hi - lo) >> 1);
        u32 c = 0;
        for (int j = t; j < m; j += 64) c += (fb[j] <= mid) ? 1u : 0u;
        #pragma unroll
        for (int off = 32; off >= 1; off >>= 1) c += __shfl_xor(c, off);
        if (c >= need) hi = mid; else lo = mid + 1;   // uniform across wave
      }
      T = ((u64)(u32)bs.x << 29) | (u64)lo;   // 41-bit threshold
    }
    if (t == 0) sT = T;
  }
  __syncthreads();

  u32 k0, k1; image_key(b, k0, k1);
  const u64 T = sT;
  const int a0 = blockIdx.x * AS;
  const u64* pa = posA + (size_t)b * NWORD;
  const float4* ab = anchors + (size_t)b * A_N;
  for (int j = t; j < AS; j += 256) {
    int a = a0 + j;
    if (a >= A_N) break;
    if (!((pa[a >> 6] >> (a & 63)) & 1ull)) continue;
    if (T != ~0ull) {
      u32 rb = rbits_for(k0, k1, (u32)a);
      if (((((u64)(rb >> 9)) << 18) | (u64)(u32)a) > T) continue;
    }
    float ax0, ay0, ax1, ay1, aar;
    conv_box(ab[a], ax0, ay0, ax1, ay1, aar);
    float bv = -1.0f; int g0 = 0;
    for (int g = 0; g < 64; g++) {
      float v = iou_pair(ax0, ay0, ax1, ay1, aar,
                         sg[0][g], sg[1][g], sg[2][g], sg[3][g], sg[4][g]);
      if (v > bv) { bv = v; g0 = g; }   // strict > = first max (jnp.argmax)
    }
    u32 r = atomicAdd(&cnt[b * G_N + g0], 1u);
    if (r < (u32)K_TOP) {
      u64 key = top4[((size_t)b * G_N + g0) * 4 + r];
      u32 fb4 = (u32)(key >> 32);
      u32 aidx = ~(u32)key;
      int o = b * (G_N * K_TOP) + g0 * K_TOP + (int)r;
      out[0 * sec + o] = (float)aidx;                // pr_inds
      out[1 * sec + o] = (float)g0;                  // gt_inds
      out[2 * sec + o] = 1.0f;                       // valid mask
      out[3 * sec + o] = __uint_as_float(fb4);       // topk ious
    }
  }
}

extern "C" void kernel_launch(void* const* d_in, const int* in_sizes, int n_in,
                              void* d_out, int out_size, void* d_ws, size_t ws_size,
                              hipStream_t stream) {
  const float4* anchors = (const float4*)d_in[0];  // [B, A, 4] cxcywh
  const float4* gt      = (const float4*)d_in[1];  // [B, G, 4] cxcywh
  float* out = (float*)d_out;                      // 4 x [B, G*K] concatenated

  // Layout — 1,988,672 B, UNDER the R5..R15-proven 2,025,536 B extent:
  //   top4     @ 0          (16,384)  [written k_top4_merge, read k_count]
  //   partial  @ 16,384     (1,605,632) — dead after k_top4_merge;
  //     aliases (written only in dispatches >= 3):
  //       fine   @ 16,384    (131,072)  [k_collect]
  //       binsel @ 147,456   (64)       [k_collect]
  //   posA     @ 1,622,016  (200,704)  [single bitmap; fully ballot-stored]
  //   hist     @ 1,822,720  (131,072)  [zeroed by k_thresh; live from k_main]
  //   small    @ 1,953,792  (2,112): npos(32) fcnt(32) cnt(2,048)
  //            [zeroed by k_thresh s==0,half==0 blocks]
  //   thr_part @ 1,955,904  (32,768)  [written k_thresh, read k_main]
  char* ws = (char*)d_ws;
  u64*  top4    = (u64*)(ws);
  u64*  partial = (u64*)(ws + 16384);
  u32*  fine    = (u32*)(ws + 16384);
  int2* binsel  = (int2*)(ws + 147456);
  u64*  posA    = (u64*)(ws + 1622016);
  u32*  hist    = (u32*)(ws + 1822720);
  u32*  npos    = (u32*)(ws + 1953792);
  u32*  fcnt    = (u32*)(ws + 1953824);
  u32*  cnt     = (u32*)(ws + 1953856);
  u32*  thr_prt = (u32*)(ws + 1955904);

  int sec = out_size / 4;  // 2048 = B*G*K

  k_thresh    <<<dim3(SUB_SL, B_IMG, 2), 512, 0, stream>>>(anchors, gt, thr_prt, hist, npos, fcnt, cnt, out, sec);
  k_main      <<<dim3(NS, B_IMG), 512, 0, stream>>>(anchors, gt, thr_prt, partial, posA, hist, npos);
  k_top4_merge<<<dim3(G_N, B_IMG), 64, 0, stream>>>(partial, top4, posA, hist, npos);
  k_collect   <<<dim3(NS, B_IMG), 256, 0, stream>>>(posA, npos, hist, binsel, fine, fcnt);
  k_count     <<<dim3(NS, B_IMG), 256, 0, stream>>>(anchors, gt, posA, binsel, fine, fcnt, cnt, top4, out, sec);
}